// Round 7
// baseline (484.261 us; speedup 1.0000x reference)
//
#include <hip/hip_runtime.h>
#include <math.h>

#define NN 50000
#define NE 800000
#define HD 64
#define NB 196  // ceil(50000/256)

typedef float f32x4 __attribute__((ext_vector_type(4)));
typedef short short8 __attribute__((ext_vector_type(8)));

__device__ __forceinline__ float wave_sum(float v) {
  #pragma unroll
  for (int off = 32; off > 0; off >>= 1) v += __shfl_xor(v, off, 64);
  return v;
}

__device__ __forceinline__ unsigned short f2bf_sw(float f) {
  union { float f; unsigned u; } v; v.f = f;
  unsigned r = v.u + 0x7FFF + ((v.u >> 16) & 1);  // RNE
  return (unsigned short)(r >> 16);
}

// packed f32x2 -> bf16x2 (1 HW instruction on gfx950)
__device__ __forceinline__ unsigned f2bf_pk(float a, float b) {
#if __has_builtin(__builtin_amdgcn_cvt_pk_bf16_f32)
  typedef __bf16 bf16x2 __attribute__((ext_vector_type(2)));
  union { bf16x2 v; unsigned u; } cv;
  cv.v = __builtin_amdgcn_cvt_pk_bf16_f32(a, b);
  return cv.u;
#else
  return (unsigned)f2bf_sw(a) | ((unsigned)f2bf_sw(b) << 16);
#endif
}
__device__ __forceinline__ unsigned short f2bf(float a) {
#if __has_builtin(__builtin_amdgcn_cvt_pk_bf16_f32)
  return (unsigned short)(f2bf_pk(a, a) & 0xFFFF);
#else
  return f2bf_sw(a);
#endif
}
__device__ __forceinline__ float bf2f(unsigned short b) {
  union { unsigned u; float f; } v; v.u = ((unsigned)b) << 16;
  return v.f;
}

// ---------------- edge prep: edge_type + per-(dst,rel) histogram ----------------
__global__ __launch_bounds__(256) void edge_prep(
    const int* __restrict__ ei, const float* __restrict__ ea,
    int* __restrict__ et, int* __restrict__ cntR)
{
  int e = blockIdx.x * blockDim.x + threadIdx.x;
  if (e >= NE) return;
  float dist = ea[e * 6];
  const float q1 = log1pf(5000.0f);
  const float q2 = log1pf(10000.0f);
  int r = (dist > q1 ? 1 : 0) + (dist > q2 ? 1 : 0);
  et[e] = r;
  int d = ei[NE + e];
  atomicAdd(&cntR[d * 3 + r], 1);
}

// ---------------- CSR build (relation-sorted: runs r=0,1,2 per node) ----------------
__global__ __launch_bounds__(256) void scanA(const int* __restrict__ cntR, int* __restrict__ bsum) {
  __shared__ int sd[256];
  int n = blockIdx.x * 256 + threadIdx.x;
  int deg = 0;
  if (n < NN) deg = cntR[3 * n] + cntR[3 * n + 1] + cntR[3 * n + 2];
  sd[threadIdx.x] = deg;
  __syncthreads();
  #pragma unroll
  for (int s = 128; s > 0; s >>= 1) {
    if (threadIdx.x < s) sd[threadIdx.x] += sd[threadIdx.x + s];
    __syncthreads();
  }
  if (threadIdx.x == 0) bsum[blockIdx.x] = sd[0];
}

__global__ __launch_bounds__(256) void scanB(int* __restrict__ bsum) {
  __shared__ int sd[256];
  int v = (threadIdx.x < NB) ? bsum[threadIdx.x] : 0;
  sd[threadIdx.x] = v;
  __syncthreads();
  for (int s = 1; s < 256; s <<= 1) {
    int t = (threadIdx.x >= s) ? sd[threadIdx.x - s] : 0;
    __syncthreads();
    sd[threadIdx.x] += t;
    __syncthreads();
  }
  if (threadIdx.x < NB) bsum[threadIdx.x] = sd[threadIdx.x] - v;  // exclusive
}

__global__ __launch_bounds__(256) void scanC(
    const int* __restrict__ cntR, const int* __restrict__ bsum,
    int* __restrict__ off3, int* __restrict__ cursor3, float* __restrict__ dinv)
{
  __shared__ int sd[256];
  int n = blockIdx.x * 256 + threadIdx.x;
  int c0 = 0, c1 = 0, c2 = 0;
  if (n < NN) { c0 = cntR[3 * n]; c1 = cntR[3 * n + 1]; c2 = cntR[3 * n + 2]; }
  int deg = c0 + c1 + c2;
  sd[threadIdx.x] = deg;
  __syncthreads();
  for (int s = 1; s < 256; s <<= 1) {
    int t = (threadIdx.x >= s) ? sd[threadIdx.x - s] : 0;
    __syncthreads();
    sd[threadIdx.x] += t;
    __syncthreads();
  }
  if (n < NN) {
    int o = bsum[blockIdx.x] + sd[threadIdx.x] - deg;
    off3[3 * n + 0] = o;           cursor3[3 * n + 0] = o;
    off3[3 * n + 1] = o + c0;      cursor3[3 * n + 1] = o + c0;
    off3[3 * n + 2] = o + c0 + c1; cursor3[3 * n + 2] = o + c0 + c1;
    dinv[3 * n + 0] = 1.0f / (float)(c0 > 1 ? c0 : 1);
    dinv[3 * n + 1] = 1.0f / (float)(c1 > 1 ? c1 : 1);
    dinv[3 * n + 2] = 1.0f / (float)(c2 > 1 ? c2 : 1);
  }
}

__global__ __launch_bounds__(256) void scatter_kernel(
    const int* __restrict__ ei, const int* __restrict__ et,
    int* __restrict__ cursor3, int* __restrict__ sorted)
{
  int e = blockIdx.x * blockDim.x + threadIdx.x;
  if (e >= NE) return;
  int s = ei[e], d = ei[NE + e], r = et[e];
  int pos = atomicAdd(&cursor3[d * 3 + r], 1);
  sorted[pos] = s;  // src only; relation implied by run
}

// ---------------- layer-0 aggregation from CSR: thread per node, run-wise ----------------
__global__ __launch_bounds__(256) void agg0_csr(
    const float* __restrict__ x, const int* __restrict__ off3, const int* __restrict__ cntR,
    const int* __restrict__ sorted, float* __restrict__ agg0)
{
  int n = blockIdx.x * blockDim.x + threadIdx.x;
  if (n >= NN) return;
  #pragma unroll
  for (int r = 0; r < 3; r++) {
    int st = off3[3 * n + r], len = cntR[3 * n + r];
    float ax = 0.f, ay = 0.f, az = 0.f;
    for (int i = 0; i < len; i++) {
      int s = sorted[st + i];
      ax += x[s * 3 + 0];
      ay += x[s * 3 + 1];
      az += x[s * 3 + 2];
    }
    agg0[n * 9 + r * 3 + 0] = ax;
    agg0[n * 9 + r * 3 + 1] = ay;
    agg0[n * 9 + r * 3 + 2] = az;
  }
}

// ---------------- pack decoder W1 (256 rows) and W2 (32x16) into B-fragment order ------------
__global__ __launch_bounds__(256) void pack_w(
    const float* __restrict__ W1, const float* __restrict__ W2,
    unsigned short* __restrict__ pk, unsigned short* __restrict__ pk2)
{
  for (int idx = threadIdx.x; idx < 8192; idx += 256) {
    int j = idx & 7, l = (idx >> 3) & 63, nt = (idx >> 9) & 1, t = idx >> 10;
    int k = t * 32 + (l >> 4) * 8 + j;
    int n = nt * 16 + (l & 15);
    pk[idx] = f2bf(W1[k * 32 + n]);
  }
  for (int idx = threadIdx.x; idx < 512; idx += 256) {
    int j = idx & 7, l = idx >> 3;
    int k = (l >> 4) * 8 + j, n = l & 15;
    pk2[idx] = f2bf(W2[k * 16 + n]);
  }
}

// ---------------- pack node-layer weights [root|W0|W1|W2] (256x64) into B-frag order ---------
__global__ __launch_bounds__(256) void pack_node_w(
    const float* __restrict__ root, const float* __restrict__ W, unsigned short* __restrict__ pkL)
{
  for (int idx = threadIdx.x; idx < 16384; idx += 256) {
    int j = idx & 7, l = (idx >> 3) & 63, nt = (idx >> 9) & 3, t = idx >> 11;
    int k = t * 32 + (l >> 4) * 8 + j;
    int n = nt * 16 + (l & 15);
    float w = (k < 64) ? root[k * 64 + n]
                       : W[((k - 64) >> 6) * 4096 + (k & 63) * 64 + n];
    pkL[idx] = f2bf(w);
  }
}

// ---- CSR aggregation: one wave/node, bf16 gather from compact hb (stride 64),
// ---- dinv-prescaled bf16 store into hcat cols 64..255
__global__ __launch_bounds__(256) void agg_csr(
    const unsigned short* __restrict__ hb, unsigned short* __restrict__ hcat,
    const int* __restrict__ off3, const int* __restrict__ cntR,
    const int* __restrict__ sorted, const float* __restrict__ dinv)
{
  int wid = (blockIdx.x * blockDim.x + threadIdx.x) >> 6;
  int lane = threadIdx.x & 63;
  if (wid >= NN) return;
  #pragma unroll
  for (int r = 0; r < 3; r++) {
    int st = off3[wid * 3 + r], len = cntR[wid * 3 + r];
    float a = 0.f;
    for (int base = 0; base < len; base += 64) {
      int cnt = len - base; if (cnt > 64) cnt = 64;
      int ent = (lane < cnt) ? sorted[st + base + lane] : 0;
      for (int j = 0; j < cnt; j++) {
        int s = __shfl(ent, j, 64);
        a += bf2f(hb[(size_t)s * HD + lane]);
      }
    }
    hcat[(size_t)wid * 256 + 64 + r * 64 + lane] = f2bf(a * dinv[wid * 3 + r]);
  }
}

// ---------------- layer 0 node update (IN=3) + relu + residual + LN ----------------
__global__ __launch_bounds__(256) void node0_kernel(
    const float* __restrict__ x, const float* __restrict__ agg0, const float* __restrict__ dinv,
    const float* __restrict__ w0, const float* __restrict__ root0, const float* __restrict__ b0,
    const float* __restrict__ res_w, const float* __restrict__ res_b,
    const float* __restrict__ g, const float* __restrict__ bb,
    float* __restrict__ h1, unsigned short* __restrict__ hcat, unsigned short* __restrict__ hb)
{
  int wid = __builtin_amdgcn_readfirstlane((int)((blockIdx.x * blockDim.x + threadIdx.x) >> 6));
  int lane = threadIdx.x & 63;
  int n0 = wid * 8;
  if (n0 >= NN) return;
  float wr[3], ww[9], wres[3];
  #pragma unroll
  for (int i = 0; i < 3; i++) { wr[i] = root0[i * HD + lane]; wres[i] = res_w[i * HD + lane]; }
  #pragma unroll
  for (int i = 0; i < 9; i++) ww[i] = w0[i * HD + lane];
  float vb = b0[lane], vrb = res_b[lane], vg = g[lane], vbb = bb[lane];
  #pragma unroll
  for (int k = 0; k < 8; k++) {
    int nk = n0 + k;
    float xv[3];
    #pragma unroll
    for (int i = 0; i < 3; i++) xv[i] = x[nk * 3 + i];
    float v = vb;
    #pragma unroll
    for (int i = 0; i < 3; i++) v = fmaf(xv[i], wr[i], v);
    #pragma unroll
    for (int r = 0; r < 3; r++) {
      float s = 0.f;
      #pragma unroll
      for (int i = 0; i < 3; i++) s = fmaf(agg0[nk * 9 + r * 3 + i], ww[r * 3 + i], s);
      v = fmaf(dinv[nk * 3 + r], s, v);
    }
    v = fmaxf(v, 0.f);
    float res = vrb;
    #pragma unroll
    for (int i = 0; i < 3; i++) res = fmaf(xv[i], wres[i], res);
    float t = v + res;
    float mu = wave_sum(t) * 0.015625f;
    float dt = t - mu;
    float var = wave_sum(dt * dt) * 0.015625f;
    float o = dt * rsqrtf(var + 1e-5f) * vg + vbb;
    h1[nk * HD + lane] = o;
    unsigned short ob = f2bf(o);
    hcat[(size_t)nk * 256 + lane] = ob;
    hb[(size_t)nk * HD + lane] = ob;
  }
}

// ---- node update as MFMA GEMM: [h|agg*dinv] (16x256 bf16) @ [root|W0|W1|W2] (256x64) --------
// ---- + relu + fp32 residual + LN. Writes: compact hb always; hcat h-cols + fp32 hout only
// ---- when hout != nullptr (i.e. when another GNN layer follows).
__global__ __launch_bounds__(256) void node_mfma(
    unsigned short* __restrict__ hcat, const float* __restrict__ hres,
    const unsigned short* __restrict__ pkL,
    const float* __restrict__ bias, const float* __restrict__ g, const float* __restrict__ bb,
    float* __restrict__ hout, unsigned short* __restrict__ hb)
{
  int wid = (blockIdx.x * blockDim.x + threadIdx.x) >> 6;
  int lane = threadIdx.x & 63;
  int n0 = wid * 16;
  if (n0 >= NN) return;
  int m = lane & 15, gq = lane >> 4;

  const short8* Ap = (const short8*)(hcat + (size_t)(n0 + m) * 256 + gq * 8);
  const short8* Bp = (const short8*)pkL;
  f32x4 acc[4];
  #pragma unroll
  for (int nt = 0; nt < 4; nt++) acc[nt] = (f32x4){0.f, 0.f, 0.f, 0.f};
  #pragma unroll
  for (int t = 0; t < 8; t++) {
    short8 a = Ap[t * 4];
    #pragma unroll
    for (int nt = 0; nt < 4; nt++)
      acc[nt] = __builtin_amdgcn_mfma_f32_16x16x32_bf16(a, Bp[(t * 4 + nt) * 64 + lane], acc[nt], 0, 0, 0);
  }

  float bias_v[4], g_v[4], bb_v[4];
  #pragma unroll
  for (int nt = 0; nt < 4; nt++) {
    bias_v[nt] = bias[nt * 16 + m];
    g_v[nt] = g[nt * 16 + m];
    bb_v[nt] = bb[nt * 16 + m];
  }
  #pragma unroll
  for (int r = 0; r < 4; r++) {
    int node = n0 + gq * 4 + r;   // C layout: row = quad*4 + reg
    float tv[4], s = 0.f;
    #pragma unroll
    for (int nt = 0; nt < 4; nt++) {
      float v = fmaxf(acc[nt][r] + bias_v[nt], 0.f) + hres[(size_t)node * HD + nt * 16 + m];
      tv[nt] = v; s += v;
    }
    #pragma unroll
    for (int o = 1; o < 16; o <<= 1) s += __shfl_xor(s, o, 64);
    float mu = s * 0.015625f;
    float s2 = 0.f;
    #pragma unroll
    for (int nt = 0; nt < 4; nt++) { float dd = tv[nt] - mu; s2 += dd * dd; }
    #pragma unroll
    for (int o = 1; o < 16; o <<= 1) s2 += __shfl_xor(s2, o, 64);
    float rstd = rsqrtf(s2 * 0.015625f + 1e-5f);
    #pragma unroll
    for (int nt = 0; nt < 4; nt++) {
      float o = (tv[nt] - mu) * rstd * g_v[nt] + bb_v[nt];
      unsigned short ob = f2bf(o);
      hb[(size_t)node * HD + nt * 16 + m] = ob;
      if (hout) {
        hout[(size_t)node * HD + nt * 16 + m] = o;
        hcat[(size_t)node * 256 + nt * 16 + m] = ob;
      }
    }
  }
}

// ---------------- decoder: 16 edges/wave, MFMA for all three layers ----------------
__global__ __launch_bounds__(256) void decoder_mfma(
    const unsigned short* __restrict__ hb, const int* __restrict__ ei, const float* __restrict__ ea,
    const unsigned short* __restrict__ pk, const unsigned short* __restrict__ pk2,
    const float* __restrict__ W1f, const float* __restrict__ B1,
    const float* __restrict__ B2, const float* __restrict__ W3, const float* __restrict__ B3,
    float* __restrict__ out)
{
  __shared__ float lds[4 * 32 * 19];
  int wv = threadIdx.x >> 6;
  int lane = threadIdx.x & 63;
  int e0 = (blockIdx.x * 4 + wv) * 16;
  int m = lane & 15, g = lane >> 4;

  int s = ei[e0 + m], d = ei[NE + e0 + m];
  short8 hs0 = *(const short8*)(hb + (size_t)s * HD + g * 8);
  short8 hs1 = *(const short8*)(hb + (size_t)s * HD + 32 + g * 8);
  short8 hd0 = *(const short8*)(hb + (size_t)d * HD + g * 8);
  short8 hd1 = *(const short8*)(hb + (size_t)d * HD + 32 + g * 8);

  union { short8 s8; unsigned u[4]; } ad0, ad1, pd0, pd1;
  #pragma unroll
  for (int j2 = 0; j2 < 4; j2++) {
    float aA = bf2f((unsigned short)hs0[2 * j2]),     bA = bf2f((unsigned short)hd0[2 * j2]);
    float aB = bf2f((unsigned short)hs0[2 * j2 + 1]), bB = bf2f((unsigned short)hd0[2 * j2 + 1]);
    float cA = bf2f((unsigned short)hs1[2 * j2]),     dA = bf2f((unsigned short)hd1[2 * j2]);
    float cB = bf2f((unsigned short)hs1[2 * j2 + 1]), dB = bf2f((unsigned short)hd1[2 * j2 + 1]);
    ad0.u[j2] = f2bf_pk(fabsf(aA - bA), fabsf(aB - bB));
    ad1.u[j2] = f2bf_pk(fabsf(cA - dA), fabsf(cB - dB));
    pd0.u[j2] = f2bf_pk(aA * bA, aB * bB);
    pd1.u[j2] = f2bf_pk(cA * dA, cB * dB);
  }

  short8 A[8] = {hs0, hs1, hd0, hd1, ad0.s8, ad1.s8, pd0.s8, pd1.s8};
  const short8* pkv = (const short8*)pk;
  f32x4 acc0 = {0.f, 0.f, 0.f, 0.f};
  f32x4 acc1 = {0.f, 0.f, 0.f, 0.f};
  #pragma unroll
  for (int t = 0; t < 8; t++) {
    acc0 = __builtin_amdgcn_mfma_f32_16x16x32_bf16(A[t], pkv[(t * 2 + 0) * 64 + lane], acc0, 0, 0, 0);
    acc1 = __builtin_amdgcn_mfma_f32_16x16x32_bf16(A[t], pkv[(t * 2 + 1) * 64 + lane], acc1, 0, 0, 0);
  }

  int cn = lane & 15;
  float wt0[6], wt1[6];
  #pragma unroll
  for (int k = 0; k < 6; k++) {
    wt0[k] = W1f[(256 + k) * 32 + cn];
    wt1[k] = W1f[(256 + k) * 32 + 16 + cn];
  }
  float b1a = B1[cn], b1b = B1[16 + cn];
  float* Z = lds + wv * 608;
  #pragma unroll
  for (int r = 0; r < 4; r++) {
    int mr = g * 4 + r;
    float z0 = acc0[r] + b1a;
    float z1 = acc1[r] + b1b;
    #pragma unroll
    for (int k = 0; k < 6; k++) {
      float eav = ea[(size_t)(e0 + mr) * 6 + k];
      z0 = fmaf(eav, wt0[k], z0);
      z1 = fmaf(eav, wt1[k], z1);
    }
    Z[cn * 19 + mr]        = fmaxf(z0, 0.f);
    Z[(16 + cn) * 19 + mr] = fmaxf(z1, 0.f);
  }

  union { short8 s8; unsigned u[4]; } A2;
  #pragma unroll
  for (int j2 = 0; j2 < 4; j2++)
    A2.u[j2] = f2bf_pk(Z[(g * 8 + 2 * j2) * 19 + m], Z[(g * 8 + 2 * j2 + 1) * 19 + m]);
  f32x4 acc2 = {0.f, 0.f, 0.f, 0.f};
  acc2 = __builtin_amdgcn_mfma_f32_16x16x32_bf16(A2.s8, ((const short8*)pk2)[lane], acc2, 0, 0, 0);

  float bias2 = B2[m];
  float w3v = W3[m];
  float t0 = fmaxf(acc2[0] + bias2, 0.f) * w3v;
  float t1 = fmaxf(acc2[1] + bias2, 0.f) * w3v;
  float t2 = fmaxf(acc2[2] + bias2, 0.f) * w3v;
  float t3 = fmaxf(acc2[3] + bias2, 0.f) * w3v;
  #pragma unroll
  for (int off = 1; off < 16; off <<= 1) {
    t0 += __shfl_xor(t0, off, 64);
    t1 += __shfl_xor(t1, off, 64);
    t2 += __shfl_xor(t2, off, 64);
    t3 += __shfl_xor(t3, off, 64);
  }
  if (m < 4) {
    float val = (m == 0) ? t0 : (m == 1) ? t1 : (m == 2) ? t2 : t3;
    out[e0 + g * 4 + m] = val + B3[0];
  }
}

extern "C" void kernel_launch(void* const* d_in, const int* in_sizes, int n_in,
                              void* d_out, int out_size, void* d_ws, size_t ws_size,
                              hipStream_t stream) {
  const float* x      = (const float*)d_in[0];
  const int*   ei     = (const int*)d_in[1];
  const float* ea     = (const float*)d_in[2];
  const float* w0     = (const float*)d_in[3];
  const float* root0  = (const float*)d_in[4];
  const float* b0     = (const float*)d_in[5];
  const float* w1     = (const float*)d_in[6];
  const float* root1  = (const float*)d_in[7];
  const float* b1     = (const float*)d_in[8];
  const float* w2     = (const float*)d_in[9];
  const float* root2  = (const float*)d_in[10];
  const float* b2     = (const float*)d_in[11];
  const float* ln_g0  = (const float*)d_in[12];
  const float* ln_b0  = (const float*)d_in[13];
  const float* ln_g1  = (const float*)d_in[14];
  const float* ln_b1  = (const float*)d_in[15];
  const float* ln_g2  = (const float*)d_in[16];
  const float* ln_b2  = (const float*)d_in[17];
  const float* res_w  = (const float*)d_in[18];
  const float* res_b  = (const float*)d_in[19];
  const float* dec_w1 = (const float*)d_in[20];
  const float* dec_b1 = (const float*)d_in[21];
  const float* dec_w2 = (const float*)d_in[22];
  const float* dec_b2 = (const float*)d_in[23];
  const float* dec_w3 = (const float*)d_in[24];
  const float* dec_b3 = (const float*)d_in[25];

  char* ws = (char*)d_ws;
  int*   et      = (int*)(ws + 0);             //  3,200,000 B
  int*   cntR    = (int*)(ws + 3200000);       //    600,000 B  (memset 0)
  float* agg0    = (float*)(ws + 3800000);     //  1,800,000 B
  int*   bsum    = (int*)(ws + 5600000);       //      1,024 B
  int*   off3    = (int*)(ws + 5601024);       //    600,000 B
  int*   cursor3 = (int*)(ws + 6201024);       //    600,000 B
  float* dinv    = (float*)(ws + 6801024);     //    600,000 B
  int*   sorted  = (int*)(ws + 7401024);       //  3,200,000 B
  float* h1      = (float*)(ws + 10601024);    // 12,800,000 B
  float* h2      = (float*)(ws + 23401024);    // 12,800,000 B
  unsigned short* hcat = (unsigned short*)(ws + 36201024);  // 25,600,000 B
  unsigned short* pkw  = (unsigned short*)(ws + 61801024);  //     16,384 B
  unsigned short* pkw2 = (unsigned short*)(ws + 61817408);  //      1,024 B
  unsigned short* pkl1 = (unsigned short*)(ws + 61818432);  //     32,768 B
  unsigned short* pkl2 = (unsigned short*)(ws + 61851200);  //     32,768 B
  unsigned short* hb   = (unsigned short*)(ws + 61883968);  //  6,400,000 B (end 68,283,968)

  hipMemsetAsync(cntR, 0, 600000, stream);

  edge_prep<<<(NE + 255) / 256, 256, 0, stream>>>(ei, ea, et, cntR);
  scanA<<<NB, 256, 0, stream>>>(cntR, bsum);
  scanB<<<1, 256, 0, stream>>>(bsum);
  scanC<<<NB, 256, 0, stream>>>(cntR, bsum, off3, cursor3, dinv);
  scatter_kernel<<<(NE + 255) / 256, 256, 0, stream>>>(ei, et, cursor3, sorted);
  pack_w<<<1, 256, 0, stream>>>(dec_w1, dec_w2, pkw, pkw2);
  pack_node_w<<<1, 256, 0, stream>>>(root1, w1, pkl1);
  pack_node_w<<<1, 256, 0, stream>>>(root2, w2, pkl2);
  agg0_csr<<<NB, 256, 0, stream>>>(x, off3, cntR, sorted, agg0);

  const int node0_blocks = (NN / 8 + 3) / 4;          // 8 nodes/wave
  const int agg_blocks   = (NN + 3) / 4;              // 1 node/wave
  const int mfma_blocks  = ((NN + 15) / 16 + 3) / 4;  // 16 nodes/wave

  node0_kernel<<<node0_blocks, 256, 0, stream>>>(x, agg0, dinv, w0, root0, b0,
                                                 res_w, res_b, ln_g0, ln_b0, h1, hcat, hb);

  agg_csr<<<agg_blocks, 256, 0, stream>>>(hb, hcat, off3, cntR, sorted, dinv);
  node_mfma<<<mfma_blocks, 256, 0, stream>>>(hcat, h1, pkl1, b1, ln_g1, ln_b1, h2, hb);

  agg_csr<<<agg_blocks, 256, 0, stream>>>(hb, hcat, off3, cntR, sorted, dinv);
  node_mfma<<<mfma_blocks, 256, 0, stream>>>(hcat, h2, pkl2, b2, ln_g2, ln_b2, nullptr, hb);

  decoder_mfma<<<NE / 64, 256, 0, stream>>>(hb, ei, ea, pkw, pkw2, dec_w1, dec_b1,
                                            dec_b2, dec_w3, dec_b3, (float*)d_out);
}

// Round 8
// 435.936 us; speedup vs baseline: 1.1109x; 1.1109x over previous
//
#include <hip/hip_runtime.h>
#include <math.h>

#define NN 50000
#define NE 800000
#define HD 64
#define NB 196  // ceil(50000/256)

typedef float f32x4 __attribute__((ext_vector_type(4)));
typedef short short8 __attribute__((ext_vector_type(8)));

__device__ __forceinline__ float wave_sum(float v) {
  #pragma unroll
  for (int off = 32; off > 0; off >>= 1) v += __shfl_xor(v, off, 64);
  return v;
}

__device__ __forceinline__ unsigned short f2bf_sw(float f) {
  union { float f; unsigned u; } v; v.f = f;
  unsigned r = v.u + 0x7FFF + ((v.u >> 16) & 1);  // RNE
  return (unsigned short)(r >> 16);
}

// packed f32x2 -> bf16x2 (1 HW instruction on gfx950)
__device__ __forceinline__ unsigned f2bf_pk(float a, float b) {
#if __has_builtin(__builtin_amdgcn_cvt_pk_bf16_f32)
  typedef __bf16 bf16x2 __attribute__((ext_vector_type(2)));
  union { bf16x2 v; unsigned u; } cv;
  cv.v = __builtin_amdgcn_cvt_pk_bf16_f32(a, b);
  return cv.u;
#else
  return (unsigned)f2bf_sw(a) | ((unsigned)f2bf_sw(b) << 16);
#endif
}
__device__ __forceinline__ unsigned short f2bf(float a) {
#if __has_builtin(__builtin_amdgcn_cvt_pk_bf16_f32)
  return (unsigned short)(f2bf_pk(a, a) & 0xFFFF);
#else
  return f2bf_sw(a);
#endif
}
__device__ __forceinline__ float bf2f(unsigned short b) {
  union { unsigned u; float f; } v; v.u = ((unsigned)b) << 16;
  return v.f;
}

// ---------------- edge prep: per-(dst,rel) histogram only ----------------
__global__ __launch_bounds__(256) void edge_prep(
    const int* __restrict__ ei, const float* __restrict__ ea,
    int* __restrict__ cntR)
{
  int e = blockIdx.x * blockDim.x + threadIdx.x;
  if (e >= NE) return;
  float dist = ea[e * 6];
  const float q1 = log1pf(5000.0f);
  const float q2 = log1pf(10000.0f);
  int r = (dist > q1 ? 1 : 0) + (dist > q2 ? 1 : 0);
  int d = ei[NE + e];
  atomicAdd(&cntR[d * 3 + r], 1);
}

// ---------------- CSR build (relation-sorted: runs r=0,1,2 per node) ----------------
__global__ __launch_bounds__(256) void scanA(const int* __restrict__ cntR, int* __restrict__ bsum) {
  __shared__ int sd[256];
  int n = blockIdx.x * 256 + threadIdx.x;
  int deg = 0;
  if (n < NN) deg = cntR[3 * n] + cntR[3 * n + 1] + cntR[3 * n + 2];
  sd[threadIdx.x] = deg;
  __syncthreads();
  #pragma unroll
  for (int s = 128; s > 0; s >>= 1) {
    if (threadIdx.x < s) sd[threadIdx.x] += sd[threadIdx.x + s];
    __syncthreads();
  }
  if (threadIdx.x == 0) bsum[blockIdx.x] = sd[0];
}

__global__ __launch_bounds__(256) void scanB(int* __restrict__ bsum) {
  __shared__ int sd[256];
  int v = (threadIdx.x < NB) ? bsum[threadIdx.x] : 0;
  sd[threadIdx.x] = v;
  __syncthreads();
  for (int s = 1; s < 256; s <<= 1) {
    int t = (threadIdx.x >= s) ? sd[threadIdx.x - s] : 0;
    __syncthreads();
    sd[threadIdx.x] += t;
    __syncthreads();
  }
  if (threadIdx.x < NB) bsum[threadIdx.x] = sd[threadIdx.x] - v;  // exclusive
}

__global__ __launch_bounds__(256) void scanC(
    const int* __restrict__ cntR, const int* __restrict__ bsum,
    int* __restrict__ off3, int* __restrict__ cursor3, float* __restrict__ dinv)
{
  __shared__ int sd[256];
  int n = blockIdx.x * 256 + threadIdx.x;
  int c0 = 0, c1 = 0, c2 = 0;
  if (n < NN) { c0 = cntR[3 * n]; c1 = cntR[3 * n + 1]; c2 = cntR[3 * n + 2]; }
  int deg = c0 + c1 + c2;
  sd[threadIdx.x] = deg;
  __syncthreads();
  for (int s = 1; s < 256; s <<= 1) {
    int t = (threadIdx.x >= s) ? sd[threadIdx.x - s] : 0;
    __syncthreads();
    sd[threadIdx.x] += t;
    __syncthreads();
  }
  if (n < NN) {
    int o = bsum[blockIdx.x] + sd[threadIdx.x] - deg;
    off3[3 * n + 0] = o;           cursor3[3 * n + 0] = o;
    off3[3 * n + 1] = o + c0;      cursor3[3 * n + 1] = o + c0;
    off3[3 * n + 2] = o + c0 + c1; cursor3[3 * n + 2] = o + c0 + c1;
    dinv[3 * n + 0] = 1.0f / (float)(c0 > 1 ? c0 : 1);
    dinv[3 * n + 1] = 1.0f / (float)(c1 > 1 ? c1 : 1);
    dinv[3 * n + 2] = 1.0f / (float)(c2 > 1 ? c2 : 1);
  }
}

// scatter: recomputes r from ea (no et buffer)
__global__ __launch_bounds__(256) void scatter_kernel(
    const int* __restrict__ ei, const float* __restrict__ ea,
    int* __restrict__ cursor3, int* __restrict__ sorted)
{
  int e = blockIdx.x * blockDim.x + threadIdx.x;
  if (e >= NE) return;
  float dist = ea[e * 6];
  const float q1 = log1pf(5000.0f);
  const float q2 = log1pf(10000.0f);
  int r = (dist > q1 ? 1 : 0) + (dist > q2 ? 1 : 0);
  int s = ei[e], d = ei[NE + e];
  int pos = atomicAdd(&cursor3[d * 3 + r], 1);
  sorted[pos] = s;  // src only; relation implied by run
}

// ---------------- layer-0 aggregation from CSR: thread per node, run-wise ----------------
__global__ __launch_bounds__(256) void agg0_csr(
    const float* __restrict__ x, const int* __restrict__ off3, const int* __restrict__ cntR,
    const int* __restrict__ sorted, float* __restrict__ agg0)
{
  int n = blockIdx.x * blockDim.x + threadIdx.x;
  if (n >= NN) return;
  #pragma unroll
  for (int r = 0; r < 3; r++) {
    int st = off3[3 * n + r], len = cntR[3 * n + r];
    float ax = 0.f, ay = 0.f, az = 0.f;
    for (int i = 0; i < len; i++) {
      int s = sorted[st + i];
      ax += x[s * 3 + 0];
      ay += x[s * 3 + 1];
      az += x[s * 3 + 2];
    }
    agg0[n * 9 + r * 3 + 0] = ax;
    agg0[n * 9 + r * 3 + 1] = ay;
    agg0[n * 9 + r * 3 + 2] = az;
  }
}

// ---------------- pack decoder W1 (256 rows) and W2 (32x16) into B-fragment order ------------
__global__ __launch_bounds__(256) void pack_w(
    const float* __restrict__ W1, const float* __restrict__ W2,
    unsigned short* __restrict__ pk, unsigned short* __restrict__ pk2)
{
  for (int idx = threadIdx.x; idx < 8192; idx += 256) {
    int j = idx & 7, l = (idx >> 3) & 63, nt = (idx >> 9) & 1, t = idx >> 10;
    int k = t * 32 + (l >> 4) * 8 + j;
    int n = nt * 16 + (l & 15);
    pk[idx] = f2bf(W1[k * 32 + n]);
  }
  for (int idx = threadIdx.x; idx < 512; idx += 256) {
    int j = idx & 7, l = idx >> 3;
    int k = (l >> 4) * 8 + j, n = l & 15;
    pk2[idx] = f2bf(W2[k * 16 + n]);
  }
}

// ---------------- pack node-layer weights [root|W0|W1|W2] (256x64) into B-frag order ---------
__global__ __launch_bounds__(256) void pack_node_w(
    const float* __restrict__ root, const float* __restrict__ W, unsigned short* __restrict__ pkL)
{
  for (int idx = threadIdx.x; idx < 16384; idx += 256) {
    int j = idx & 7, l = (idx >> 3) & 63, nt = (idx >> 9) & 3, t = idx >> 11;
    int k = t * 32 + (l >> 4) * 8 + j;
    int n = nt * 16 + (l & 15);
    float w = (k < 64) ? root[k * 64 + n]
                       : W[((k - 64) >> 6) * 4096 + (k & 63) * 64 + n];
    pkL[idx] = f2bf(w);
  }
}

// ---- CSR aggregation v2: 2 nodes per wave (32 lanes each), dword gathers (2 feats/lane).
// ---- Each half processes its own node's runs concurrently -> 2 edges in flight per wave iter.
// ---- dinv-prescaled bf16 store into hcat cols 64..255.
__global__ __launch_bounds__(256) void agg_csr(
    const unsigned short* __restrict__ hb, unsigned short* __restrict__ hcat,
    const int* __restrict__ off3, const int* __restrict__ cntR,
    const int* __restrict__ sorted, const float* __restrict__ dinv)
{
  int wid = (blockIdx.x * blockDim.x + threadIdx.x) >> 6;
  int lane = threadIdx.x & 63;
  int half = lane >> 5;
  int c = lane & 31;              // dword index: features 2c, 2c+1
  int n = wid * 2 + half;         // NN=50000 even, grid sized so n < NN always
  if (wid * 2 >= NN) return;
  const unsigned* hb32 = (const unsigned*)hb;
  unsigned* hcat32 = (unsigned*)hcat;
  #pragma unroll
  for (int r = 0; r < 3; r++) {
    int st = off3[n * 3 + r], len = cntR[n * 3 + r];
    float a0 = 0.f, a1 = 0.f;
    for (int base = 0; base < len; base += 32) {
      int cnt = len - base; if (cnt > 32) cnt = 32;
      int ent = (c < cnt) ? sorted[st + base + c] : 0;
      // per-half broadcast: source lane = half*32 + j; halves advance independently
      for (int j = 0; j < cnt; j++) {
        int e = __shfl(ent, half * 32 + j, 64);
        unsigned u = hb32[(size_t)e * 32 + c];
        a0 += bf2f((unsigned short)(u & 0xFFFF));
        a1 += bf2f((unsigned short)(u >> 16));
      }
    }
    float dv = dinv[n * 3 + r];
    hcat32[(size_t)n * 128 + 32 + r * 32 + c] = f2bf_pk(a0 * dv, a1 * dv);
  }
}

// ---------------- layer 0 node update (IN=3) + relu + residual + LN ----------------
__global__ __launch_bounds__(256) void node0_kernel(
    const float* __restrict__ x, const float* __restrict__ agg0, const float* __restrict__ dinv,
    const float* __restrict__ w0, const float* __restrict__ root0, const float* __restrict__ b0,
    const float* __restrict__ res_w, const float* __restrict__ res_b,
    const float* __restrict__ g, const float* __restrict__ bb,
    float* __restrict__ h1, unsigned short* __restrict__ hcat, unsigned short* __restrict__ hb)
{
  int wid = __builtin_amdgcn_readfirstlane((int)((blockIdx.x * blockDim.x + threadIdx.x) >> 6));
  int lane = threadIdx.x & 63;
  int n0 = wid * 8;
  if (n0 >= NN) return;
  float wr[3], ww[9], wres[3];
  #pragma unroll
  for (int i = 0; i < 3; i++) { wr[i] = root0[i * HD + lane]; wres[i] = res_w[i * HD + lane]; }
  #pragma unroll
  for (int i = 0; i < 9; i++) ww[i] = w0[i * HD + lane];
  float vb = b0[lane], vrb = res_b[lane], vg = g[lane], vbb = bb[lane];
  #pragma unroll
  for (int k = 0; k < 8; k++) {
    int nk = n0 + k;
    float xv[3];
    #pragma unroll
    for (int i = 0; i < 3; i++) xv[i] = x[nk * 3 + i];
    float v = vb;
    #pragma unroll
    for (int i = 0; i < 3; i++) v = fmaf(xv[i], wr[i], v);
    #pragma unroll
    for (int r = 0; r < 3; r++) {
      float s = 0.f;
      #pragma unroll
      for (int i = 0; i < 3; i++) s = fmaf(agg0[nk * 9 + r * 3 + i], ww[r * 3 + i], s);
      v = fmaf(dinv[nk * 3 + r], s, v);
    }
    v = fmaxf(v, 0.f);
    float res = vrb;
    #pragma unroll
    for (int i = 0; i < 3; i++) res = fmaf(xv[i], wres[i], res);
    float t = v + res;
    float mu = wave_sum(t) * 0.015625f;
    float dt = t - mu;
    float var = wave_sum(dt * dt) * 0.015625f;
    float o = dt * rsqrtf(var + 1e-5f) * vg + vbb;
    h1[nk * HD + lane] = o;
    unsigned short ob = f2bf(o);
    hcat[(size_t)nk * 256 + lane] = ob;
    hb[(size_t)nk * HD + lane] = ob;
  }
}

// ---- node update as MFMA GEMM: [h|agg*dinv] (16x256 bf16) @ [root|W0|W1|W2] (256x64) --------
__global__ __launch_bounds__(256) void node_mfma(
    unsigned short* __restrict__ hcat, const float* __restrict__ hres,
    const unsigned short* __restrict__ pkL,
    const float* __restrict__ bias, const float* __restrict__ g, const float* __restrict__ bb,
    float* __restrict__ hout, unsigned short* __restrict__ hb)
{
  int wid = (blockIdx.x * blockDim.x + threadIdx.x) >> 6;
  int lane = threadIdx.x & 63;
  int n0 = wid * 16;
  if (n0 >= NN) return;
  int m = lane & 15, gq = lane >> 4;

  const short8* Ap = (const short8*)(hcat + (size_t)(n0 + m) * 256 + gq * 8);
  const short8* Bp = (const short8*)pkL;
  f32x4 acc[4];
  #pragma unroll
  for (int nt = 0; nt < 4; nt++) acc[nt] = (f32x4){0.f, 0.f, 0.f, 0.f};
  #pragma unroll
  for (int t = 0; t < 8; t++) {
    short8 a = Ap[t * 4];
    #pragma unroll
    for (int nt = 0; nt < 4; nt++)
      acc[nt] = __builtin_amdgcn_mfma_f32_16x16x32_bf16(a, Bp[(t * 4 + nt) * 64 + lane], acc[nt], 0, 0, 0);
  }

  float bias_v[4], g_v[4], bb_v[4];
  #pragma unroll
  for (int nt = 0; nt < 4; nt++) {
    bias_v[nt] = bias[nt * 16 + m];
    g_v[nt] = g[nt * 16 + m];
    bb_v[nt] = bb[nt * 16 + m];
  }
  #pragma unroll
  for (int r = 0; r < 4; r++) {
    int node = n0 + gq * 4 + r;   // C layout: row = quad*4 + reg
    float tv[4], s = 0.f;
    #pragma unroll
    for (int nt = 0; nt < 4; nt++) {
      float v = fmaxf(acc[nt][r] + bias_v[nt], 0.f) + hres[(size_t)node * HD + nt * 16 + m];
      tv[nt] = v; s += v;
    }
    #pragma unroll
    for (int o = 1; o < 16; o <<= 1) s += __shfl_xor(s, o, 64);
    float mu = s * 0.015625f;
    float s2 = 0.f;
    #pragma unroll
    for (int nt = 0; nt < 4; nt++) { float dd = tv[nt] - mu; s2 += dd * dd; }
    #pragma unroll
    for (int o = 1; o < 16; o <<= 1) s2 += __shfl_xor(s2, o, 64);
    float rstd = rsqrtf(s2 * 0.015625f + 1e-5f);
    #pragma unroll
    for (int nt = 0; nt < 4; nt++) {
      float o = (tv[nt] - mu) * rstd * g_v[nt] + bb_v[nt];
      unsigned short ob = f2bf(o);
      hb[(size_t)node * HD + nt * 16 + m] = ob;
      if (hout) {
        hout[(size_t)node * HD + nt * 16 + m] = o;
        hcat[(size_t)node * 256 + nt * 16 + m] = ob;
      }
    }
  }
}

// ---------------- decoder: 16 edges/wave, MFMA for all three layers ----------------
__global__ __launch_bounds__(256) void decoder_mfma(
    const unsigned short* __restrict__ hb, const int* __restrict__ ei, const float* __restrict__ ea,
    const unsigned short* __restrict__ pk, const unsigned short* __restrict__ pk2,
    const float* __restrict__ W1f, const float* __restrict__ B1,
    const float* __restrict__ B2, const float* __restrict__ W3, const float* __restrict__ B3,
    float* __restrict__ out)
{
  __shared__ float lds[4 * 32 * 19];
  int wv = threadIdx.x >> 6;
  int lane = threadIdx.x & 63;
  int e0 = (blockIdx.x * 4 + wv) * 16;
  int m = lane & 15, g = lane >> 4;

  int s = ei[e0 + m], d = ei[NE + e0 + m];
  short8 hs0 = *(const short8*)(hb + (size_t)s * HD + g * 8);
  short8 hs1 = *(const short8*)(hb + (size_t)s * HD + 32 + g * 8);
  short8 hd0 = *(const short8*)(hb + (size_t)d * HD + g * 8);
  short8 hd1 = *(const short8*)(hb + (size_t)d * HD + 32 + g * 8);

  union { short8 s8; unsigned u[4]; } ad0, ad1, pd0, pd1;
  #pragma unroll
  for (int j2 = 0; j2 < 4; j2++) {
    float aA = bf2f((unsigned short)hs0[2 * j2]),     bA = bf2f((unsigned short)hd0[2 * j2]);
    float aB = bf2f((unsigned short)hs0[2 * j2 + 1]), bB = bf2f((unsigned short)hd0[2 * j2 + 1]);
    float cA = bf2f((unsigned short)hs1[2 * j2]),     dA = bf2f((unsigned short)hd1[2 * j2]);
    float cB = bf2f((unsigned short)hs1[2 * j2 + 1]), dB = bf2f((unsigned short)hd1[2 * j2 + 1]);
    ad0.u[j2] = f2bf_pk(fabsf(aA - bA), fabsf(aB - bB));
    ad1.u[j2] = f2bf_pk(fabsf(cA - dA), fabsf(cB - dB));
    pd0.u[j2] = f2bf_pk(aA * bA, aB * bB);
    pd1.u[j2] = f2bf_pk(cA * dA, cB * dB);
  }

  short8 A[8] = {hs0, hs1, hd0, hd1, ad0.s8, ad1.s8, pd0.s8, pd1.s8};
  const short8* pkv = (const short8*)pk;
  f32x4 acc0 = {0.f, 0.f, 0.f, 0.f};
  f32x4 acc1 = {0.f, 0.f, 0.f, 0.f};
  #pragma unroll
  for (int t = 0; t < 8; t++) {
    acc0 = __builtin_amdgcn_mfma_f32_16x16x32_bf16(A[t], pkv[(t * 2 + 0) * 64 + lane], acc0, 0, 0, 0);
    acc1 = __builtin_amdgcn_mfma_f32_16x16x32_bf16(A[t], pkv[(t * 2 + 1) * 64 + lane], acc1, 0, 0, 0);
  }

  int cn = lane & 15;
  float wt0[6], wt1[6];
  #pragma unroll
  for (int k = 0; k < 6; k++) {
    wt0[k] = W1f[(256 + k) * 32 + cn];
    wt1[k] = W1f[(256 + k) * 32 + 16 + cn];
  }
  float b1a = B1[cn], b1b = B1[16 + cn];
  float* Z = lds + wv * 608;
  #pragma unroll
  for (int r = 0; r < 4; r++) {
    int mr = g * 4 + r;
    float z0 = acc0[r] + b1a;
    float z1 = acc1[r] + b1b;
    #pragma unroll
    for (int k = 0; k < 6; k++) {
      float eav = ea[(size_t)(e0 + mr) * 6 + k];
      z0 = fmaf(eav, wt0[k], z0);
      z1 = fmaf(eav, wt1[k], z1);
    }
    Z[cn * 19 + mr]        = fmaxf(z0, 0.f);
    Z[(16 + cn) * 19 + mr] = fmaxf(z1, 0.f);
  }

  union { short8 s8; unsigned u[4]; } A2;
  #pragma unroll
  for (int j2 = 0; j2 < 4; j2++)
    A2.u[j2] = f2bf_pk(Z[(g * 8 + 2 * j2) * 19 + m], Z[(g * 8 + 2 * j2 + 1) * 19 + m]);
  f32x4 acc2 = {0.f, 0.f, 0.f, 0.f};
  acc2 = __builtin_amdgcn_mfma_f32_16x16x32_bf16(A2.s8, ((const short8*)pk2)[lane], acc2, 0, 0, 0);

  float bias2 = B2[m];
  float w3v = W3[m];
  float t0 = fmaxf(acc2[0] + bias2, 0.f) * w3v;
  float t1 = fmaxf(acc2[1] + bias2, 0.f) * w3v;
  float t2 = fmaxf(acc2[2] + bias2, 0.f) * w3v;
  float t3 = fmaxf(acc2[3] + bias2, 0.f) * w3v;
  #pragma unroll
  for (int off = 1; off < 16; off <<= 1) {
    t0 += __shfl_xor(t0, off, 64);
    t1 += __shfl_xor(t1, off, 64);
    t2 += __shfl_xor(t2, off, 64);
    t3 += __shfl_xor(t3, off, 64);
  }
  if (m < 4) {
    float val = (m == 0) ? t0 : (m == 1) ? t1 : (m == 2) ? t2 : t3;
    out[e0 + g * 4 + m] = val + B3[0];
  }
}

extern "C" void kernel_launch(void* const* d_in, const int* in_sizes, int n_in,
                              void* d_out, int out_size, void* d_ws, size_t ws_size,
                              hipStream_t stream) {
  const float* x      = (const float*)d_in[0];
  const int*   ei     = (const int*)d_in[1];
  const float* ea     = (const float*)d_in[2];
  const float* w0     = (const float*)d_in[3];
  const float* root0  = (const float*)d_in[4];
  const float* b0     = (const float*)d_in[5];
  const float* w1     = (const float*)d_in[6];
  const float* root1  = (const float*)d_in[7];
  const float* b1     = (const float*)d_in[8];
  const float* w2     = (const float*)d_in[9];
  const float* root2  = (const float*)d_in[10];
  const float* b2     = (const float*)d_in[11];
  const float* ln_g0  = (const float*)d_in[12];
  const float* ln_b0  = (const float*)d_in[13];
  const float* ln_g1  = (const float*)d_in[14];
  const float* ln_b1  = (const float*)d_in[15];
  const float* ln_g2  = (const float*)d_in[16];
  const float* ln_b2  = (const float*)d_in[17];
  const float* res_w  = (const float*)d_in[18];
  const float* res_b  = (const float*)d_in[19];
  const float* dec_w1 = (const float*)d_in[20];
  const float* dec_b1 = (const float*)d_in[21];
  const float* dec_w2 = (const float*)d_in[22];
  const float* dec_b2 = (const float*)d_in[23];
  const float* dec_w3 = (const float*)d_in[24];
  const float* dec_b3 = (const float*)d_in[25];

  char* ws = (char*)d_ws;
  int*   cntR    = (int*)(ws + 3200000);       //    600,000 B  (memset 0)
  float* agg0    = (float*)(ws + 3800000);     //  1,800,000 B
  int*   bsum    = (int*)(ws + 5600000);       //      1,024 B
  int*   off3    = (int*)(ws + 5601024);       //    600,000 B
  int*   cursor3 = (int*)(ws + 6201024);       //    600,000 B
  float* dinv    = (float*)(ws + 6801024);     //    600,000 B
  int*   sorted  = (int*)(ws + 7401024);       //  3,200,000 B
  float* h1      = (float*)(ws + 10601024);    // 12,800,000 B
  float* h2      = (float*)(ws + 23401024);    // 12,800,000 B
  unsigned short* hcat = (unsigned short*)(ws + 36201024);  // 25,600,000 B
  unsigned short* pkw  = (unsigned short*)(ws + 61801024);  //     16,384 B
  unsigned short* pkw2 = (unsigned short*)(ws + 61817408);  //      1,024 B
  unsigned short* pkl1 = (unsigned short*)(ws + 61818432);  //     32,768 B
  unsigned short* pkl2 = (unsigned short*)(ws + 61851200);  //     32,768 B
  unsigned short* hb   = (unsigned short*)(ws + 61883968);  //  6,400,000 B (end 68,283,968)

  hipMemsetAsync(cntR, 0, 600000, stream);

  edge_prep<<<(NE + 255) / 256, 256, 0, stream>>>(ei, ea, cntR);
  scanA<<<NB, 256, 0, stream>>>(cntR, bsum);
  scanB<<<1, 256, 0, stream>>>(bsum);
  scanC<<<NB, 256, 0, stream>>>(cntR, bsum, off3, cursor3, dinv);
  scatter_kernel<<<(NE + 255) / 256, 256, 0, stream>>>(ei, ea, cursor3, sorted);
  pack_w<<<1, 256, 0, stream>>>(dec_w1, dec_w2, pkw, pkw2);
  pack_node_w<<<1, 256, 0, stream>>>(root1, w1, pkl1);
  pack_node_w<<<1, 256, 0, stream>>>(root2, w2, pkl2);
  agg0_csr<<<NB, 256, 0, stream>>>(x, off3, cntR, sorted, agg0);

  const int node0_blocks = (NN / 8 + 3) / 4;          // 8 nodes/wave
  const int agg_blocks   = (NN / 2 + 3) / 4;          // 2 nodes/wave, 4 waves/block
  const int mfma_blocks  = ((NN + 15) / 16 + 3) / 4;  // 16 nodes/wave

  node0_kernel<<<node0_blocks, 256, 0, stream>>>(x, agg0, dinv, w0, root0, b0,
                                                 res_w, res_b, ln_g0, ln_b0, h1, hcat, hb);

  agg_csr<<<agg_blocks, 256, 0, stream>>>(hb, hcat, off3, cntR, sorted, dinv);
  node_mfma<<<mfma_blocks, 256, 0, stream>>>(hcat, h1, pkl1, b1, ln_g1, ln_b1, h2, hb);

  agg_csr<<<agg_blocks, 256, 0, stream>>>(hb, hcat, off3, cntR, sorted, dinv);
  node_mfma<<<mfma_blocks, 256, 0, stream>>>(hcat, h2, pkl2, b2, ln_g2, ln_b2, nullptr, hb);

  decoder_mfma<<<NE / 64, 256, 0, stream>>>(hb, ei, ea, pkw, pkw2, dec_w1, dec_b1,
                                            dec_b2, dec_w3, dec_b3, (float*)d_out);
}

// Round 9
// 427.206 us; speedup vs baseline: 1.1336x; 1.0204x over previous
//
#include <hip/hip_runtime.h>
#include <math.h>

#define NN 50000
#define NE 800000
#define HD 64
#define NB 196  // ceil(50000/256)

typedef float f32x4 __attribute__((ext_vector_type(4)));
typedef float f32x16 __attribute__((ext_vector_type(16)));
typedef short short8 __attribute__((ext_vector_type(8)));

__device__ __forceinline__ float wave_sum(float v) {
  #pragma unroll
  for (int off = 32; off > 0; off >>= 1) v += __shfl_xor(v, off, 64);
  return v;
}

__device__ __forceinline__ unsigned short f2bf_sw(float f) {
  union { float f; unsigned u; } v; v.f = f;
  unsigned r = v.u + 0x7FFF + ((v.u >> 16) & 1);  // RNE
  return (unsigned short)(r >> 16);
}

// packed f32x2 -> bf16x2 (1 HW instruction on gfx950)
__device__ __forceinline__ unsigned f2bf_pk(float a, float b) {
#if __has_builtin(__builtin_amdgcn_cvt_pk_bf16_f32)
  typedef __bf16 bf16x2 __attribute__((ext_vector_type(2)));
  union { bf16x2 v; unsigned u; } cv;
  cv.v = __builtin_amdgcn_cvt_pk_bf16_f32(a, b);
  return cv.u;
#else
  return (unsigned)f2bf_sw(a) | ((unsigned)f2bf_sw(b) << 16);
#endif
}
__device__ __forceinline__ unsigned short f2bf(float a) {
#if __has_builtin(__builtin_amdgcn_cvt_pk_bf16_f32)
  return (unsigned short)(f2bf_pk(a, a) & 0xFFFF);
#else
  return f2bf_sw(a);
#endif
}
__device__ __forceinline__ float bf2f(unsigned short b) {
  union { unsigned u; float f; } v; v.u = ((unsigned)b) << 16;
  return v.f;
}

// ---------------- edge prep: per-(dst,rel) histogram only ----------------
__global__ __launch_bounds__(256) void edge_prep(
    const int* __restrict__ ei, const float* __restrict__ ea,
    int* __restrict__ cntR)
{
  int e = blockIdx.x * blockDim.x + threadIdx.x;
  if (e >= NE) return;
  float dist = ea[e * 6];
  const float q1 = log1pf(5000.0f);
  const float q2 = log1pf(10000.0f);
  int r = (dist > q1 ? 1 : 0) + (dist > q2 ? 1 : 0);
  int d = ei[NE + e];
  atomicAdd(&cntR[d * 3 + r], 1);
}

// ---------------- CSR build (relation-sorted: runs r=0,1,2 per node) ----------------
__global__ __launch_bounds__(256) void scanA(const int* __restrict__ cntR, int* __restrict__ bsum) {
  __shared__ int sd[256];
  int n = blockIdx.x * 256 + threadIdx.x;
  int deg = 0;
  if (n < NN) deg = cntR[3 * n] + cntR[3 * n + 1] + cntR[3 * n + 2];
  sd[threadIdx.x] = deg;
  __syncthreads();
  #pragma unroll
  for (int s = 128; s > 0; s >>= 1) {
    if (threadIdx.x < s) sd[threadIdx.x] += sd[threadIdx.x + s];
    __syncthreads();
  }
  if (threadIdx.x == 0) bsum[blockIdx.x] = sd[0];
}

__global__ __launch_bounds__(256) void scanB(int* __restrict__ bsum) {
  __shared__ int sd[256];
  int v = (threadIdx.x < NB) ? bsum[threadIdx.x] : 0;
  sd[threadIdx.x] = v;
  __syncthreads();
  for (int s = 1; s < 256; s <<= 1) {
    int t = (threadIdx.x >= s) ? sd[threadIdx.x - s] : 0;
    __syncthreads();
    sd[threadIdx.x] += t;
    __syncthreads();
  }
  if (threadIdx.x < NB) bsum[threadIdx.x] = sd[threadIdx.x] - v;  // exclusive
}

__global__ __launch_bounds__(256) void scanC(
    const int* __restrict__ cntR, const int* __restrict__ bsum,
    int* __restrict__ off3, int* __restrict__ cursor3, float* __restrict__ dinv)
{
  __shared__ int sd[256];
  int n = blockIdx.x * 256 + threadIdx.x;
  int c0 = 0, c1 = 0, c2 = 0;
  if (n < NN) { c0 = cntR[3 * n]; c1 = cntR[3 * n + 1]; c2 = cntR[3 * n + 2]; }
  int deg = c0 + c1 + c2;
  sd[threadIdx.x] = deg;
  __syncthreads();
  for (int s = 1; s < 256; s <<= 1) {
    int t = (threadIdx.x >= s) ? sd[threadIdx.x - s] : 0;
    __syncthreads();
    sd[threadIdx.x] += t;
    __syncthreads();
  }
  if (n < NN) {
    int o = bsum[blockIdx.x] + sd[threadIdx.x] - deg;
    off3[3 * n + 0] = o;           cursor3[3 * n + 0] = o;
    off3[3 * n + 1] = o + c0;      cursor3[3 * n + 1] = o + c0;
    off3[3 * n + 2] = o + c0 + c1; cursor3[3 * n + 2] = o + c0 + c1;
    dinv[3 * n + 0] = 1.0f / (float)(c0 > 1 ? c0 : 1);
    dinv[3 * n + 1] = 1.0f / (float)(c1 > 1 ? c1 : 1);
    dinv[3 * n + 2] = 1.0f / (float)(c2 > 1 ? c2 : 1);
  }
}

// scatter: recomputes r from ea (no et buffer)
__global__ __launch_bounds__(256) void scatter_kernel(
    const int* __restrict__ ei, const float* __restrict__ ea,
    int* __restrict__ cursor3, int* __restrict__ sorted)
{
  int e = blockIdx.x * blockDim.x + threadIdx.x;
  if (e >= NE) return;
  float dist = ea[e * 6];
  const float q1 = log1pf(5000.0f);
  const float q2 = log1pf(10000.0f);
  int r = (dist > q1 ? 1 : 0) + (dist > q2 ? 1 : 0);
  int s = ei[e], d = ei[NE + e];
  int pos = atomicAdd(&cursor3[d * 3 + r], 1);
  sorted[pos] = s;  // src only; relation implied by run
}

// ---------------- layer-0 aggregation from CSR: thread per node, run-wise ----------------
__global__ __launch_bounds__(256) void agg0_csr(
    const float* __restrict__ x, const int* __restrict__ off3, const int* __restrict__ cntR,
    const int* __restrict__ sorted, float* __restrict__ agg0)
{
  int n = blockIdx.x * blockDim.x + threadIdx.x;
  if (n >= NN) return;
  #pragma unroll
  for (int r = 0; r < 3; r++) {
    int st = off3[3 * n + r], len = cntR[3 * n + r];
    float ax = 0.f, ay = 0.f, az = 0.f;
    for (int i = 0; i < len; i++) {
      int s = sorted[st + i];
      ax += x[s * 3 + 0];
      ay += x[s * 3 + 1];
      az += x[s * 3 + 2];
    }
    agg0[n * 9 + r * 3 + 0] = ax;
    agg0[n * 9 + r * 3 + 1] = ay;
    agg0[n * 9 + r * 3 + 2] = az;
  }
}

// ---- pack decoder W1ext (272 rows x 32 cols, rows>=262 zero) into 32x32x16 B-frag order -----
// ---- pk3[(t*64+lane)*8+j] = W1ext[16t + 8*(lane>>5) + j][lane&31], t = 0..16
// ---- and W2 (32x16) into 16x16x32 B-frag order (pk2)
__global__ __launch_bounds__(256) void pack_w(
    const float* __restrict__ W1, const float* __restrict__ W2,
    unsigned short* __restrict__ pk3, unsigned short* __restrict__ pk2)
{
  for (int idx = threadIdx.x; idx < 8704; idx += 256) {
    int j = idx & 7, l = (idx >> 3) & 63, t = idx >> 9;
    int k = 16 * t + 8 * (l >> 5) + j;
    int n = l & 31;
    pk3[idx] = (k < 262) ? f2bf(W1[k * 32 + n]) : (unsigned short)0;
  }
  for (int idx = threadIdx.x; idx < 512; idx += 256) {
    int j = idx & 7, l = idx >> 3;
    int k = (l >> 4) * 8 + j, n = l & 15;
    pk2[idx] = f2bf(W2[k * 16 + n]);
  }
}

// ---------------- pack node-layer weights [root|W0|W1|W2] (256x64) into B-frag order ---------
__global__ __launch_bounds__(256) void pack_node_w(
    const float* __restrict__ root, const float* __restrict__ W, unsigned short* __restrict__ pkL)
{
  for (int idx = threadIdx.x; idx < 16384; idx += 256) {
    int j = idx & 7, l = (idx >> 3) & 63, nt = (idx >> 9) & 3, t = idx >> 11;
    int k = t * 32 + (l >> 4) * 8 + j;
    int n = nt * 16 + (l & 15);
    float w = (k < 64) ? root[k * 64 + n]
                       : W[((k - 64) >> 6) * 4096 + (k & 63) * 64 + n];
    pkL[idx] = f2bf(w);
  }
}

// ---- CSR aggregation v2: 2 nodes per wave (32 lanes each), dword gathers (2 feats/lane) -----
__global__ __launch_bounds__(256) void agg_csr(
    const unsigned short* __restrict__ hb, unsigned short* __restrict__ hcat,
    const int* __restrict__ off3, const int* __restrict__ cntR,
    const int* __restrict__ sorted, const float* __restrict__ dinv)
{
  int wid = (blockIdx.x * blockDim.x + threadIdx.x) >> 6;
  int lane = threadIdx.x & 63;
  int half = lane >> 5;
  int c = lane & 31;              // dword index: features 2c, 2c+1
  int n = wid * 2 + half;
  if (wid * 2 >= NN) return;
  const unsigned* hb32 = (const unsigned*)hb;
  unsigned* hcat32 = (unsigned*)hcat;
  #pragma unroll
  for (int r = 0; r < 3; r++) {
    int st = off3[n * 3 + r], len = cntR[n * 3 + r];
    float a0 = 0.f, a1 = 0.f;
    for (int base = 0; base < len; base += 32) {
      int cnt = len - base; if (cnt > 32) cnt = 32;
      int ent = (c < cnt) ? sorted[st + base + c] : 0;
      for (int j = 0; j < cnt; j++) {
        int e = __shfl(ent, half * 32 + j, 64);
        unsigned u = hb32[(size_t)e * 32 + c];
        a0 += bf2f((unsigned short)(u & 0xFFFF));
        a1 += bf2f((unsigned short)(u >> 16));
      }
    }
    float dv = dinv[n * 3 + r];
    hcat32[(size_t)n * 128 + 32 + r * 32 + c] = f2bf_pk(a0 * dv, a1 * dv);
  }
}

// ---------------- layer 0 node update (IN=3) + relu + residual + LN ----------------
__global__ __launch_bounds__(256) void node0_kernel(
    const float* __restrict__ x, const float* __restrict__ agg0, const float* __restrict__ dinv,
    const float* __restrict__ w0, const float* __restrict__ root0, const float* __restrict__ b0,
    const float* __restrict__ res_w, const float* __restrict__ res_b,
    const float* __restrict__ g, const float* __restrict__ bb,
    float* __restrict__ h1, unsigned short* __restrict__ hcat, unsigned short* __restrict__ hb)
{
  int wid = __builtin_amdgcn_readfirstlane((int)((blockIdx.x * blockDim.x + threadIdx.x) >> 6));
  int lane = threadIdx.x & 63;
  int n0 = wid * 8;
  if (n0 >= NN) return;
  float wr[3], ww[9], wres[3];
  #pragma unroll
  for (int i = 0; i < 3; i++) { wr[i] = root0[i * HD + lane]; wres[i] = res_w[i * HD + lane]; }
  #pragma unroll
  for (int i = 0; i < 9; i++) ww[i] = w0[i * HD + lane];
  float vb = b0[lane], vrb = res_b[lane], vg = g[lane], vbb = bb[lane];
  #pragma unroll
  for (int k = 0; k < 8; k++) {
    int nk = n0 + k;
    float xv[3];
    #pragma unroll
    for (int i = 0; i < 3; i++) xv[i] = x[nk * 3 + i];
    float v = vb;
    #pragma unroll
    for (int i = 0; i < 3; i++) v = fmaf(xv[i], wr[i], v);
    #pragma unroll
    for (int r = 0; r < 3; r++) {
      float s = 0.f;
      #pragma unroll
      for (int i = 0; i < 3; i++) s = fmaf(agg0[nk * 9 + r * 3 + i], ww[r * 3 + i], s);
      v = fmaf(dinv[nk * 3 + r], s, v);
    }
    v = fmaxf(v, 0.f);
    float res = vrb;
    #pragma unroll
    for (int i = 0; i < 3; i++) res = fmaf(xv[i], wres[i], res);
    float t = v + res;
    float mu = wave_sum(t) * 0.015625f;
    float dt = t - mu;
    float var = wave_sum(dt * dt) * 0.015625f;
    float o = dt * rsqrtf(var + 1e-5f) * vg + vbb;
    h1[nk * HD + lane] = o;
    unsigned short ob = f2bf(o);
    hcat[(size_t)nk * 256 + lane] = ob;
    hb[(size_t)nk * HD + lane] = ob;
  }
}

// ---- node update as MFMA GEMM: [h|agg*dinv] (16x256 bf16) @ [root|W0|W1|W2] (256x64) --------
__global__ __launch_bounds__(256) void node_mfma(
    unsigned short* __restrict__ hcat, const float* __restrict__ hres,
    const unsigned short* __restrict__ pkL,
    const float* __restrict__ bias, const float* __restrict__ g, const float* __restrict__ bb,
    float* __restrict__ hout, unsigned short* __restrict__ hb)
{
  int wid = (blockIdx.x * blockDim.x + threadIdx.x) >> 6;
  int lane = threadIdx.x & 63;
  int n0 = wid * 16;
  if (n0 >= NN) return;
  int m = lane & 15, gq = lane >> 4;

  const short8* Ap = (const short8*)(hcat + (size_t)(n0 + m) * 256 + gq * 8);
  const short8* Bp = (const short8*)pkL;
  f32x4 acc[4];
  #pragma unroll
  for (int nt = 0; nt < 4; nt++) acc[nt] = (f32x4){0.f, 0.f, 0.f, 0.f};
  #pragma unroll
  for (int t = 0; t < 8; t++) {
    short8 a = Ap[t * 4];
    #pragma unroll
    for (int nt = 0; nt < 4; nt++)
      acc[nt] = __builtin_amdgcn_mfma_f32_16x16x32_bf16(a, Bp[(t * 4 + nt) * 64 + lane], acc[nt], 0, 0, 0);
  }

  float bias_v[4], g_v[4], bb_v[4];
  #pragma unroll
  for (int nt = 0; nt < 4; nt++) {
    bias_v[nt] = bias[nt * 16 + m];
    g_v[nt] = g[nt * 16 + m];
    bb_v[nt] = bb[nt * 16 + m];
  }
  #pragma unroll
  for (int r = 0; r < 4; r++) {
    int node = n0 + gq * 4 + r;   // C layout: row = quad*4 + reg
    float tv[4], s = 0.f;
    #pragma unroll
    for (int nt = 0; nt < 4; nt++) {
      float v = fmaxf(acc[nt][r] + bias_v[nt], 0.f) + hres[(size_t)node * HD + nt * 16 + m];
      tv[nt] = v; s += v;
    }
    #pragma unroll
    for (int o = 1; o < 16; o <<= 1) s += __shfl_xor(s, o, 64);
    float mu = s * 0.015625f;
    float s2 = 0.f;
    #pragma unroll
    for (int nt = 0; nt < 4; nt++) { float dd = tv[nt] - mu; s2 += dd * dd; }
    #pragma unroll
    for (int o = 1; o < 16; o <<= 1) s2 += __shfl_xor(s2, o, 64);
    float rstd = rsqrtf(s2 * 0.015625f + 1e-5f);
    #pragma unroll
    for (int nt = 0; nt < 4; nt++) {
      float o = (tv[nt] - mu) * rstd * g_v[nt] + bb_v[nt];
      unsigned short ob = f2bf(o);
      hb[(size_t)node * HD + nt * 16 + m] = ob;
      if (hout) {
        hout[(size_t)node * HD + nt * 16 + m] = o;
        hcat[(size_t)node * 256 + nt * 16 + m] = ob;
      }
    }
  }
}

// ---------------- decoder v3: 32 edges/wave, 32x32x16 MFMA, ea folded into K ----------------
// K layout (272): [hs 0..63 | hd 64..127 | |hs-hd| 128..191 | hs*hd 192..255 | ea 256..261 | 0]
__global__ __launch_bounds__(256) void decoder_mfma(
    const unsigned short* __restrict__ hb, const int* __restrict__ ei, const float* __restrict__ ea,
    const unsigned short* __restrict__ pk3, const unsigned short* __restrict__ pk2,
    const float* __restrict__ B1, const float* __restrict__ B2,
    const float* __restrict__ W3, const float* __restrict__ B3,
    float* __restrict__ out)
{
  __shared__ float lds[4 * 32 * 33];   // per wave: Zt[32 cols][33] (transposed z)
  int wv = threadIdx.x >> 6;
  int lane = threadIdx.x & 63;
  int e0 = (blockIdx.x * 4 + wv) * 32;
  int r = lane & 31, u = lane >> 5;

  int s = ei[e0 + r], d = ei[NE + e0 + r];
  const unsigned short* ps = hb + (size_t)s * HD + u * 8;
  const unsigned short* pq = hb + (size_t)d * HD + u * 8;
  short8 hs[4], hd[4];
  #pragma unroll
  for (int t = 0; t < 4; t++) {
    hs[t] = *(const short8*)(ps + t * 16);   // features 16t + 8u + j
    hd[t] = *(const short8*)(pq + t * 16);
  }

  union u8 { short8 s8; unsigned w[4]; };
  u8 ad[4], pd[4];
  #pragma unroll
  for (int t = 0; t < 4; t++) {
    #pragma unroll
    for (int j2 = 0; j2 < 4; j2++) {
      float a0 = bf2f((unsigned short)hs[t][2 * j2]),     b0 = bf2f((unsigned short)hd[t][2 * j2]);
      float a1 = bf2f((unsigned short)hs[t][2 * j2 + 1]), b1 = bf2f((unsigned short)hd[t][2 * j2 + 1]);
      ad[t].w[j2] = f2bf_pk(fabsf(a0 - b0), fabsf(a1 - b1));
      pd[t].w[j2] = f2bf_pk(a0 * b0, a1 * b1);
    }
  }

  // ea fragment for K-chunk 16: lanes u==0 hold ea[edge r][0..5], rest zero
  u8 aea;
  aea.w[0] = 0; aea.w[1] = 0; aea.w[2] = 0; aea.w[3] = 0;
  if (u == 0) {
    const float* er = ea + (size_t)(e0 + r) * 6;
    float2 e01 = *(const float2*)(er);
    float2 e23 = *(const float2*)(er + 2);
    float2 e45 = *(const float2*)(er + 4);
    aea.w[0] = f2bf_pk(e01.x, e01.y);
    aea.w[1] = f2bf_pk(e23.x, e23.y);
    aea.w[2] = f2bf_pk(e45.x, e45.y);
  }

  const short8* Bp = (const short8*)pk3;
  f32x16 acc = {0.f, 0.f, 0.f, 0.f, 0.f, 0.f, 0.f, 0.f,
                0.f, 0.f, 0.f, 0.f, 0.f, 0.f, 0.f, 0.f};
  #pragma unroll
  for (int t = 0; t < 4; t++)
    acc = __builtin_amdgcn_mfma_f32_32x32x16_bf16(hs[t], Bp[t * 64 + lane], acc, 0, 0, 0);
  #pragma unroll
  for (int t = 0; t < 4; t++)
    acc = __builtin_amdgcn_mfma_f32_32x32x16_bf16(hd[t], Bp[(4 + t) * 64 + lane], acc, 0, 0, 0);
  #pragma unroll
  for (int t = 0; t < 4; t++)
    acc = __builtin_amdgcn_mfma_f32_32x32x16_bf16(ad[t].s8, Bp[(8 + t) * 64 + lane], acc, 0, 0, 0);
  #pragma unroll
  for (int t = 0; t < 4; t++)
    acc = __builtin_amdgcn_mfma_f32_32x32x16_bf16(pd[t].s8, Bp[(12 + t) * 64 + lane], acc, 0, 0, 0);
  acc = __builtin_amdgcn_mfma_f32_32x32x16_bf16(aea.s8, Bp[16 * 64 + lane], acc, 0, 0, 0);

  // phase 1: bias + relu -> LDS transposed: Zt[col][edge_row], stride 33
  // C layout: col = lane&31 (=r), row = (i&3) + 8*(i>>2) + 4u
  float* Z = lds + wv * 1056;
  float b1v = B1[r];
  #pragma unroll
  for (int i = 0; i < 16; i++) {
    int row = (i & 3) + 8 * (i >> 2) + 4 * u;
    Z[r * 33 + row] = fmaxf(acc[i] + b1v, 0.f);
  }
  // wave-private LDS: compiler inserts lgkmcnt waits; no barrier needed

  // phase 2+3: two groups of 16 edges, 16x16x32 MFMA vs W2, then W3 reduce
  int m = lane & 15, g = lane >> 4;
  float bias2 = B2[m];
  float w3v = W3[m];
  #pragma unroll
  for (int q = 0; q < 2; q++) {
    u8 A2;
    #pragma unroll
    for (int j2 = 0; j2 < 4; j2++)
      A2.w[j2] = f2bf_pk(Z[(g * 8 + 2 * j2) * 33 + q * 16 + m],
                         Z[(g * 8 + 2 * j2 + 1) * 33 + q * 16 + m]);
    f32x4 acc2 = {0.f, 0.f, 0.f, 0.f};
    acc2 = __builtin_amdgcn_mfma_f32_16x16x32_bf16(A2.s8, ((const short8*)pk2)[lane], acc2, 0, 0, 0);

    float t0 = fmaxf(acc2[0] + bias2, 0.f) * w3v;
    float t1 = fmaxf(acc2[1] + bias2, 0.f) * w3v;
    float t2 = fmaxf(acc2[2] + bias2, 0.f) * w3v;
    float t3 = fmaxf(acc2[3] + bias2, 0.f) * w3v;
    #pragma unroll
    for (int off = 1; off < 16; off <<= 1) {
      t0 += __shfl_xor(t0, off, 64);
      t1 += __shfl_xor(t1, off, 64);
      t2 += __shfl_xor(t2, off, 64);
      t3 += __shfl_xor(t3, off, 64);
    }
    if (m < 4) {
      float val = (m == 0) ? t0 : (m == 1) ? t1 : (m == 2) ? t2 : t3;
      out[e0 + q * 16 + g * 4 + m] = val + B3[0];
    }
  }
}

extern "C" void kernel_launch(void* const* d_in, const int* in_sizes, int n_in,
                              void* d_out, int out_size, void* d_ws, size_t ws_size,
                              hipStream_t stream) {
  const float* x      = (const float*)d_in[0];
  const int*   ei     = (const int*)d_in[1];
  const float* ea     = (const float*)d_in[2];
  const float* w0     = (const float*)d_in[3];
  const float* root0  = (const float*)d_in[4];
  const float* b0     = (const float*)d_in[5];
  const float* w1     = (const float*)d_in[6];
  const float* root1  = (const float*)d_in[7];
  const float* b1     = (const float*)d_in[8];
  const float* w2     = (const float*)d_in[9];
  const float* root2  = (const float*)d_in[10];
  const float* b2     = (const float*)d_in[11];
  const float* ln_g0  = (const float*)d_in[12];
  const float* ln_b0  = (const float*)d_in[13];
  const float* ln_g1  = (const float*)d_in[14];
  const float* ln_b1  = (const float*)d_in[15];
  const float* ln_g2  = (const float*)d_in[16];
  const float* ln_b2  = (const float*)d_in[17];
  const float* res_w  = (const float*)d_in[18];
  const float* res_b  = (const float*)d_in[19];
  const float* dec_w1 = (const float*)d_in[20];
  const float* dec_b1 = (const float*)d_in[21];
  const float* dec_w2 = (const float*)d_in[22];
  const float* dec_b2 = (const float*)d_in[23];
  const float* dec_w3 = (const float*)d_in[24];
  const float* dec_b3 = (const float*)d_in[25];

  char* ws = (char*)d_ws;
  int*   cntR    = (int*)(ws + 3200000);       //    600,000 B  (memset 0)
  float* agg0    = (float*)(ws + 3800000);     //  1,800,000 B
  int*   bsum    = (int*)(ws + 5600000);       //      1,024 B
  int*   off3    = (int*)(ws + 5601024);       //    600,000 B
  int*   cursor3 = (int*)(ws + 6201024);       //    600,000 B
  float* dinv    = (float*)(ws + 6801024);     //    600,000 B
  int*   sorted  = (int*)(ws + 7401024);       //  3,200,000 B
  float* h1      = (float*)(ws + 10601024);    // 12,800,000 B
  float* h2      = (float*)(ws + 23401024);    // 12,800,000 B
  unsigned short* hcat = (unsigned short*)(ws + 36201024);  // 25,600,000 B
  unsigned short* pk3  = (unsigned short*)(ws + 61801024);  //     17,408 B
  unsigned short* pkw2 = (unsigned short*)(ws + 61818432);  //      1,024 B
  unsigned short* pkl1 = (unsigned short*)(ws + 61819456);  //     32,768 B
  unsigned short* pkl2 = (unsigned short*)(ws + 61852224);  //     32,768 B
  unsigned short* hb   = (unsigned short*)(ws + 61884992);  //  6,400,000 B (end 68,284,992)

  hipMemsetAsync(cntR, 0, 600000, stream);

  edge_prep<<<(NE + 255) / 256, 256, 0, stream>>>(ei, ea, cntR);
  scanA<<<NB, 256, 0, stream>>>(cntR, bsum);
  scanB<<<1, 256, 0, stream>>>(bsum);
  scanC<<<NB, 256, 0, stream>>>(cntR, bsum, off3, cursor3, dinv);
  scatter_kernel<<<(NE + 255) / 256, 256, 0, stream>>>(ei, ea, cursor3, sorted);
  pack_w<<<1, 256, 0, stream>>>(dec_w1, dec_w2, pk3, pkw2);
  pack_node_w<<<1, 256, 0, stream>>>(root1, w1, pkl1);
  pack_node_w<<<1, 256, 0, stream>>>(root2, w2, pkl2);
  agg0_csr<<<NB, 256, 0, stream>>>(x, off3, cntR, sorted, agg0);

  const int node0_blocks = (NN / 8 + 3) / 4;          // 8 nodes/wave
  const int agg_blocks   = (NN / 2 + 3) / 4;          // 2 nodes/wave, 4 waves/block
  const int mfma_blocks  = ((NN + 15) / 16 + 3) / 4;  // 16 nodes/wave

  node0_kernel<<<node0_blocks, 256, 0, stream>>>(x, agg0, dinv, w0, root0, b0,
                                                 res_w, res_b, ln_g0, ln_b0, h1, hcat, hb);

  agg_csr<<<agg_blocks, 256, 0, stream>>>(hb, hcat, off3, cntR, sorted, dinv);
  node_mfma<<<mfma_blocks, 256, 0, stream>>>(hcat, h1, pkl1, b1, ln_g1, ln_b1, h2, hb);

  agg_csr<<<agg_blocks, 256, 0, stream>>>(hb, hcat, off3, cntR, sorted, dinv);
  node_mfma<<<mfma_blocks, 256, 0, stream>>>(hcat, h2, pkl2, b2, ln_g2, ln_b2, nullptr, hb);

  decoder_mfma<<<NE / 128, 256, 0, stream>>>(hb, ei, ea, pk3, pkw2, dec_b1,
                                             dec_b2, dec_w3, dec_b3, (float*)d_out);
}

// Round 10
// 405.118 us; speedup vs baseline: 1.1954x; 1.0545x over previous
//
#include <hip/hip_runtime.h>
#include <math.h>

#define NN 50000
#define NE 800000
#define HD 64
#define NB 196  // ceil(50000/256)

typedef float f32x4 __attribute__((ext_vector_type(4)));
typedef float f32x16 __attribute__((ext_vector_type(16)));
typedef short short8 __attribute__((ext_vector_type(8)));

__device__ __forceinline__ float wave_sum(float v) {
  #pragma unroll
  for (int off = 32; off > 0; off >>= 1) v += __shfl_xor(v, off, 64);
  return v;
}

__device__ __forceinline__ unsigned short f2bf_sw(float f) {
  union { float f; unsigned u; } v; v.f = f;
  unsigned r = v.u + 0x7FFF + ((v.u >> 16) & 1);  // RNE
  return (unsigned short)(r >> 16);
}

__device__ __forceinline__ unsigned f2bf_pk(float a, float b) {
#if __has_builtin(__builtin_amdgcn_cvt_pk_bf16_f32)
  typedef __bf16 bf16x2 __attribute__((ext_vector_type(2)));
  union { bf16x2 v; unsigned u; } cv;
  cv.v = __builtin_amdgcn_cvt_pk_bf16_f32(a, b);
  return cv.u;
#else
  return (unsigned)f2bf_sw(a) | ((unsigned)f2bf_sw(b) << 16);
#endif
}
__device__ __forceinline__ unsigned short f2bf(float a) {
#if __has_builtin(__builtin_amdgcn_cvt_pk_bf16_f32)
  return (unsigned short)(f2bf_pk(a, a) & 0xFFFF);
#else
  return f2bf_sw(a);
#endif
}
__device__ __forceinline__ float bf2f(unsigned short b) {
  union { unsigned u; float f; } v; v.u = ((unsigned)b) << 16;
  return v.f;
}

// ---------------- edge prep: histogram + 1-byte relation cache ----------------
__global__ __launch_bounds__(256) void edge_prep(
    const int* __restrict__ ei, const float* __restrict__ ea,
    int* __restrict__ cntR, unsigned char* __restrict__ r8)
{
  int e = blockIdx.x * blockDim.x + threadIdx.x;
  if (e >= NE) return;
  float dist = ea[e * 6];
  const float q1 = log1pf(5000.0f);
  const float q2 = log1pf(10000.0f);
  int r = (dist > q1 ? 1 : 0) + (dist > q2 ? 1 : 0);
  r8[e] = (unsigned char)r;
  int d = ei[NE + e];
  atomicAdd(&cntR[d * 3 + r], 1);
}

// ---------------- CSR build (relation-sorted: runs r=0,1,2 per node) ----------------
__global__ __launch_bounds__(256) void scanA(const int* __restrict__ cntR, int* __restrict__ bsum) {
  __shared__ int sd[256];
  int n = blockIdx.x * 256 + threadIdx.x;
  int deg = 0;
  if (n < NN) deg = cntR[3 * n] + cntR[3 * n + 1] + cntR[3 * n + 2];
  sd[threadIdx.x] = deg;
  __syncthreads();
  #pragma unroll
  for (int s = 128; s > 0; s >>= 1) {
    if (threadIdx.x < s) sd[threadIdx.x] += sd[threadIdx.x + s];
    __syncthreads();
  }
  if (threadIdx.x == 0) bsum[blockIdx.x] = sd[0];
}

__global__ __launch_bounds__(256) void scanB(int* __restrict__ bsum) {
  __shared__ int sd[256];
  int v = (threadIdx.x < NB) ? bsum[threadIdx.x] : 0;
  sd[threadIdx.x] = v;
  __syncthreads();
  for (int s = 1; s < 256; s <<= 1) {
    int t = (threadIdx.x >= s) ? sd[threadIdx.x - s] : 0;
    __syncthreads();
    sd[threadIdx.x] += t;
    __syncthreads();
  }
  if (threadIdx.x < NB) bsum[threadIdx.x] = sd[threadIdx.x] - v;  // exclusive
}

__global__ __launch_bounds__(256) void scanC(
    const int* __restrict__ cntR, const int* __restrict__ bsum,
    int* __restrict__ off3, int* __restrict__ cursor3, float* __restrict__ dinv)
{
  __shared__ int sd[256];
  int n = blockIdx.x * 256 + threadIdx.x;
  int c0 = 0, c1 = 0, c2 = 0;
  if (n < NN) { c0 = cntR[3 * n]; c1 = cntR[3 * n + 1]; c2 = cntR[3 * n + 2]; }
  int deg = c0 + c1 + c2;
  sd[threadIdx.x] = deg;
  __syncthreads();
  for (int s = 1; s < 256; s <<= 1) {
    int t = (threadIdx.x >= s) ? sd[threadIdx.x - s] : 0;
    __syncthreads();
    sd[threadIdx.x] += t;
    __syncthreads();
  }
  if (n < NN) {
    int o = bsum[blockIdx.x] + sd[threadIdx.x] - deg;
    off3[3 * n + 0] = o;           cursor3[3 * n + 0] = o;
    off3[3 * n + 1] = o + c0;      cursor3[3 * n + 1] = o + c0;
    off3[3 * n + 2] = o + c0 + c1; cursor3[3 * n + 2] = o + c0 + c1;
    dinv[3 * n + 0] = 1.0f / (float)(c0 > 1 ? c0 : 1);
    dinv[3 * n + 1] = 1.0f / (float)(c1 > 1 ? c1 : 1);
    dinv[3 * n + 2] = 1.0f / (float)(c2 > 1 ? c2 : 1);
  }
}

// scatter: reads cached 1-byte relation (no ea re-read)
__global__ __launch_bounds__(256) void scatter_kernel(
    const int* __restrict__ ei, const unsigned char* __restrict__ r8,
    int* __restrict__ cursor3, int* __restrict__ sorted)
{
  int e = blockIdx.x * blockDim.x + threadIdx.x;
  if (e >= NE) return;
  int r = r8[e];
  int s = ei[e], d = ei[NE + e];
  int pos = atomicAdd(&cursor3[d * 3 + r], 1);
  sorted[pos] = s;  // src only; relation implied by run
}

// ---- layer-0 aggregation v2: 16 nodes/wave, 4 lanes/node (lane&3 = feature, f==3 idle) -----
__global__ __launch_bounds__(256) void agg0_csr(
    const float* __restrict__ x, const int* __restrict__ off3, const int* __restrict__ cntR,
    const int* __restrict__ sorted, float* __restrict__ agg0)
{
  int wid = (blockIdx.x * blockDim.x + threadIdx.x) >> 6;
  int lane = threadIdx.x & 63;
  int n = wid * 16 + (lane >> 2);
  int f = lane & 3;
  if (n >= NN) return;
  int off = off3[3 * n];
  int c0 = cntR[3 * n], c1 = cntR[3 * n + 1], c2 = cntR[3 * n + 2];
  int c01 = c0 + c1, deg = c01 + c2;
  float a0 = 0.f, a1 = 0.f, a2 = 0.f;
  for (int i = 0; i < deg; i++) {
    int s = sorted[off + i];
    float v = (f < 3) ? x[s * 3 + f] : 0.f;
    if (i < c0) a0 += v; else if (i < c01) a1 += v; else a2 += v;
  }
  if (f < 3) {
    agg0[n * 9 + 0 + f] = a0;
    agg0[n * 9 + 3 + f] = a1;
    agg0[n * 9 + 6 + f] = a2;
  }
}

// ---------------- fused weight packing: block 0 = decoder, blocks 1/2 = node layers ----------
__global__ __launch_bounds__(256) void pack_all(
    const float* __restrict__ W1, const float* __restrict__ W2,
    const float* __restrict__ root1, const float* __restrict__ w1,
    const float* __restrict__ root2, const float* __restrict__ w2,
    unsigned short* __restrict__ pk3, unsigned short* __restrict__ pk2,
    unsigned short* __restrict__ pkl1, unsigned short* __restrict__ pkl2)
{
  if (blockIdx.x == 0) {
    // W1ext (272x32, rows>=262 zero) into 32x32x16 B-frag order
    for (int idx = threadIdx.x; idx < 8704; idx += 256) {
      int j = idx & 7, l = (idx >> 3) & 63, t = idx >> 9;
      int k = 16 * t + 8 * (l >> 5) + j;
      int n = l & 31;
      pk3[idx] = (k < 262) ? f2bf(W1[k * 32 + n]) : (unsigned short)0;
    }
    // W2 (32x16) into 16x16x32 B-frag order
    for (int idx = threadIdx.x; idx < 512; idx += 256) {
      int j = idx & 7, l = idx >> 3;
      int k = (l >> 4) * 8 + j, n = l & 15;
      pk2[idx] = f2bf(W2[k * 16 + n]);
    }
  } else {
    const float* root = (blockIdx.x == 1) ? root1 : root2;
    const float* W    = (blockIdx.x == 1) ? w1 : w2;
    unsigned short* pkL = (blockIdx.x == 1) ? pkl1 : pkl2;
    for (int idx = threadIdx.x; idx < 16384; idx += 256) {
      int j = idx & 7, l = (idx >> 3) & 63, nt = (idx >> 9) & 3, t = idx >> 11;
      int k = t * 32 + (l >> 4) * 8 + j;
      int n = nt * 16 + (l & 15);
      float w = (k < 64) ? root[k * 64 + n]
                         : W[((k - 64) >> 6) * 4096 + (k & 63) * 64 + n];
      pkL[idx] = f2bf(w);
    }
  }
}

// ---- CSR aggregation v2: 2 nodes per wave (32 lanes each), dword gathers (2 feats/lane) -----
__global__ __launch_bounds__(256) void agg_csr(
    const unsigned short* __restrict__ hb, unsigned short* __restrict__ hcat,
    const int* __restrict__ off3, const int* __restrict__ cntR,
    const int* __restrict__ sorted, const float* __restrict__ dinv)
{
  int wid = (blockIdx.x * blockDim.x + threadIdx.x) >> 6;
  int lane = threadIdx.x & 63;
  int half = lane >> 5;
  int c = lane & 31;              // dword index: features 2c, 2c+1
  int n = wid * 2 + half;
  if (wid * 2 >= NN) return;
  const unsigned* hb32 = (const unsigned*)hb;
  unsigned* hcat32 = (unsigned*)hcat;
  #pragma unroll
  for (int r = 0; r < 3; r++) {
    int st = off3[n * 3 + r], len = cntR[n * 3 + r];
    float a0 = 0.f, a1 = 0.f;
    for (int base = 0; base < len; base += 32) {
      int cnt = len - base; if (cnt > 32) cnt = 32;
      int ent = (c < cnt) ? sorted[st + base + c] : 0;
      for (int j = 0; j < cnt; j++) {
        int e = __shfl(ent, half * 32 + j, 64);
        unsigned u = hb32[(size_t)e * 32 + c];
        a0 += bf2f((unsigned short)(u & 0xFFFF));
        a1 += bf2f((unsigned short)(u >> 16));
      }
    }
    float dv = dinv[n * 3 + r];
    hcat32[(size_t)n * 128 + 32 + r * 32 + c] = f2bf_pk(a0 * dv, a1 * dv);
  }
}

// ---------------- layer 0 node update (IN=3) + relu + residual + LN; bf16 outputs only -------
__global__ __launch_bounds__(256) void node0_kernel(
    const float* __restrict__ x, const float* __restrict__ agg0, const float* __restrict__ dinv,
    const float* __restrict__ w0, const float* __restrict__ root0, const float* __restrict__ b0,
    const float* __restrict__ res_w, const float* __restrict__ res_b,
    const float* __restrict__ g, const float* __restrict__ bb,
    unsigned short* __restrict__ hcat, unsigned short* __restrict__ hb)
{
  int wid = __builtin_amdgcn_readfirstlane((int)((blockIdx.x * blockDim.x + threadIdx.x) >> 6));
  int lane = threadIdx.x & 63;
  int n0 = wid * 8;
  if (n0 >= NN) return;
  float wr[3], ww[9], wres[3];
  #pragma unroll
  for (int i = 0; i < 3; i++) { wr[i] = root0[i * HD + lane]; wres[i] = res_w[i * HD + lane]; }
  #pragma unroll
  for (int i = 0; i < 9; i++) ww[i] = w0[i * HD + lane];
  float vb = b0[lane], vrb = res_b[lane], vg = g[lane], vbb = bb[lane];
  #pragma unroll
  for (int k = 0; k < 8; k++) {
    int nk = n0 + k;
    float xv[3];
    #pragma unroll
    for (int i = 0; i < 3; i++) xv[i] = x[nk * 3 + i];
    float v = vb;
    #pragma unroll
    for (int i = 0; i < 3; i++) v = fmaf(xv[i], wr[i], v);
    #pragma unroll
    for (int r = 0; r < 3; r++) {
      float s = 0.f;
      #pragma unroll
      for (int i = 0; i < 3; i++) s = fmaf(agg0[nk * 9 + r * 3 + i], ww[r * 3 + i], s);
      v = fmaf(dinv[nk * 3 + r], s, v);
    }
    v = fmaxf(v, 0.f);
    float res = vrb;
    #pragma unroll
    for (int i = 0; i < 3; i++) res = fmaf(xv[i], wres[i], res);
    float t = v + res;
    float mu = wave_sum(t) * 0.015625f;
    float dt = t - mu;
    float var = wave_sum(dt * dt) * 0.015625f;
    float o = dt * rsqrtf(var + 1e-5f) * vg + vbb;
    unsigned short ob = f2bf(o);
    hcat[(size_t)nk * 256 + lane] = ob;
    hb[(size_t)nk * HD + lane] = ob;
  }
}

// ---- node update as MFMA GEMM; residual read as bf16 from hcat cols 0..63 (pre-overwrite) ---
__global__ __launch_bounds__(256) void node_mfma(
    unsigned short* __restrict__ hcat, const unsigned short* __restrict__ pkL,
    const float* __restrict__ bias, const float* __restrict__ g, const float* __restrict__ bb,
    unsigned short* __restrict__ hb, int write_next)
{
  int wid = (blockIdx.x * blockDim.x + threadIdx.x) >> 6;
  int lane = threadIdx.x & 63;
  int n0 = wid * 16;
  if (n0 >= NN) return;
  int m = lane & 15, gq = lane >> 4;

  const short8* Ap = (const short8*)(hcat + (size_t)(n0 + m) * 256 + gq * 8);
  const short8* Bp = (const short8*)pkL;
  f32x4 acc[4];
  #pragma unroll
  for (int nt = 0; nt < 4; nt++) acc[nt] = (f32x4){0.f, 0.f, 0.f, 0.f};
  #pragma unroll
  for (int t = 0; t < 8; t++) {
    short8 a = Ap[t * 4];
    #pragma unroll
    for (int nt = 0; nt < 4; nt++)
      acc[nt] = __builtin_amdgcn_mfma_f32_16x16x32_bf16(a, Bp[(t * 4 + nt) * 64 + lane], acc[nt], 0, 0, 0);
  }

  float bias_v[4], g_v[4], bb_v[4];
  #pragma unroll
  for (int nt = 0; nt < 4; nt++) {
    bias_v[nt] = bias[nt * 16 + m];
    g_v[nt] = g[nt * 16 + m];
    bb_v[nt] = bb[nt * 16 + m];
  }
  #pragma unroll
  for (int r = 0; r < 4; r++) {
    int node = n0 + gq * 4 + r;   // C layout: row = quad*4 + reg
    float tv[4], s = 0.f;
    #pragma unroll
    for (int nt = 0; nt < 4; nt++) {
      float res = bf2f(hcat[(size_t)node * 256 + nt * 16 + m]);  // h_prev bf16 (this lane only)
      float v = fmaxf(acc[nt][r] + bias_v[nt], 0.f) + res;
      tv[nt] = v; s += v;
    }
    #pragma unroll
    for (int o = 1; o < 16; o <<= 1) s += __shfl_xor(s, o, 64);
    float mu = s * 0.015625f;
    float s2 = 0.f;
    #pragma unroll
    for (int nt = 0; nt < 4; nt++) { float dd = tv[nt] - mu; s2 += dd * dd; }
    #pragma unroll
    for (int o = 1; o < 16; o <<= 1) s2 += __shfl_xor(s2, o, 64);
    float rstd = rsqrtf(s2 * 0.015625f + 1e-5f);
    #pragma unroll
    for (int nt = 0; nt < 4; nt++) {
      float o = (tv[nt] - mu) * rstd * g_v[nt] + bb_v[nt];
      unsigned short ob = f2bf(o);
      hb[(size_t)node * HD + nt * 16 + m] = ob;
      if (write_next) hcat[(size_t)node * 256 + nt * 16 + m] = ob;
    }
  }
}

// ---------------- decoder v3: 32 edges/wave, 32x32x16 MFMA, ea folded into K ----------------
__global__ __launch_bounds__(256) void decoder_mfma(
    const unsigned short* __restrict__ hb, const int* __restrict__ ei, const float* __restrict__ ea,
    const unsigned short* __restrict__ pk3, const unsigned short* __restrict__ pk2,
    const float* __restrict__ B1, const float* __restrict__ B2,
    const float* __restrict__ W3, const float* __restrict__ B3,
    float* __restrict__ out)
{
  __shared__ float lds[4 * 32 * 33];
  int wv = threadIdx.x >> 6;
  int lane = threadIdx.x & 63;
  int e0 = (blockIdx.x * 4 + wv) * 32;
  int r = lane & 31, u = lane >> 5;

  int s = ei[e0 + r], d = ei[NE + e0 + r];
  const unsigned short* ps = hb + (size_t)s * HD + u * 8;
  const unsigned short* pq = hb + (size_t)d * HD + u * 8;
  short8 hs[4], hd[4];
  #pragma unroll
  for (int t = 0; t < 4; t++) {
    hs[t] = *(const short8*)(ps + t * 16);
    hd[t] = *(const short8*)(pq + t * 16);
  }

  union u8 { short8 s8; unsigned w[4]; };
  u8 ad[4], pd[4];
  #pragma unroll
  for (int t = 0; t < 4; t++) {
    #pragma unroll
    for (int j2 = 0; j2 < 4; j2++) {
      float a0 = bf2f((unsigned short)hs[t][2 * j2]),     b0 = bf2f((unsigned short)hd[t][2 * j2]);
      float a1 = bf2f((unsigned short)hs[t][2 * j2 + 1]), b1 = bf2f((unsigned short)hd[t][2 * j2 + 1]);
      ad[t].w[j2] = f2bf_pk(fabsf(a0 - b0), fabsf(a1 - b1));
      pd[t].w[j2] = f2bf_pk(a0 * b0, a1 * b1);
    }
  }

  u8 aea;
  aea.w[0] = 0; aea.w[1] = 0; aea.w[2] = 0; aea.w[3] = 0;
  if (u == 0) {
    const float* er = ea + (size_t)(e0 + r) * 6;
    float2 e01 = *(const float2*)(er);
    float2 e23 = *(const float2*)(er + 2);
    float2 e45 = *(const float2*)(er + 4);
    aea.w[0] = f2bf_pk(e01.x, e01.y);
    aea.w[1] = f2bf_pk(e23.x, e23.y);
    aea.w[2] = f2bf_pk(e45.x, e45.y);
  }

  const short8* Bp = (const short8*)pk3;
  f32x16 acc = {0.f, 0.f, 0.f, 0.f, 0.f, 0.f, 0.f, 0.f,
                0.f, 0.f, 0.f, 0.f, 0.f, 0.f, 0.f, 0.f};
  #pragma unroll
  for (int t = 0; t < 4; t++)
    acc = __builtin_amdgcn_mfma_f32_32x32x16_bf16(hs[t], Bp[t * 64 + lane], acc, 0, 0, 0);
  #pragma unroll
  for (int t = 0; t < 4; t++)
    acc = __builtin_amdgcn_mfma_f32_32x32x16_bf16(hd[t], Bp[(4 + t) * 64 + lane], acc, 0, 0, 0);
  #pragma unroll
  for (int t = 0; t < 4; t++)
    acc = __builtin_amdgcn_mfma_f32_32x32x16_bf16(ad[t].s8, Bp[(8 + t) * 64 + lane], acc, 0, 0, 0);
  #pragma unroll
  for (int t = 0; t < 4; t++)
    acc = __builtin_amdgcn_mfma_f32_32x32x16_bf16(pd[t].s8, Bp[(12 + t) * 64 + lane], acc, 0, 0, 0);
  acc = __builtin_amdgcn_mfma_f32_32x32x16_bf16(aea.s8, Bp[16 * 64 + lane], acc, 0, 0, 0);

  float* Z = lds + wv * 1056;
  float b1v = B1[r];
  #pragma unroll
  for (int i = 0; i < 16; i++) {
    int row = (i & 3) + 8 * (i >> 2) + 4 * u;
    Z[r * 33 + row] = fmaxf(acc[i] + b1v, 0.f);
  }

  int m = lane & 15, g = lane >> 4;
  float bias2 = B2[m];
  float w3v = W3[m];
  #pragma unroll
  for (int q = 0; q < 2; q++) {
    u8 A2;
    #pragma unroll
    for (int j2 = 0; j2 < 4; j2++)
      A2.w[j2] = f2bf_pk(Z[(g * 8 + 2 * j2) * 33 + q * 16 + m],
                         Z[(g * 8 + 2 * j2 + 1) * 33 + q * 16 + m]);
    f32x4 acc2 = {0.f, 0.f, 0.f, 0.f};
    acc2 = __builtin_amdgcn_mfma_f32_16x16x32_bf16(A2.s8, ((const short8*)pk2)[lane], acc2, 0, 0, 0);

    float t0 = fmaxf(acc2[0] + bias2, 0.f) * w3v;
    float t1 = fmaxf(acc2[1] + bias2, 0.f) * w3v;
    float t2 = fmaxf(acc2[2] + bias2, 0.f) * w3v;
    float t3 = fmaxf(acc2[3] + bias2, 0.f) * w3v;
    // select-merge butterfly: lane m ends holding sum of t_{m&3} over 16 lanes
    int b0 = m & 1, b1 = m & 2;
    float s01 = (b0 ? t1 : t0) + __shfl_xor(b0 ? t0 : t1, 1, 64);
    float s23 = (b0 ? t3 : t2) + __shfl_xor(b0 ? t2 : t3, 1, 64);
    float sv  = (b1 ? s23 : s01) + __shfl_xor(b1 ? s01 : s23, 2, 64);
    sv += __shfl_xor(sv, 4, 64);
    sv += __shfl_xor(sv, 8, 64);
    if (m < 4) out[e0 + q * 16 + g * 4 + m] = sv + B3[0];
  }
}

extern "C" void kernel_launch(void* const* d_in, const int* in_sizes, int n_in,
                              void* d_out, int out_size, void* d_ws, size_t ws_size,
                              hipStream_t stream) {
  const float* x      = (const float*)d_in[0];
  const int*   ei     = (const int*)d_in[1];
  const float* ea     = (const float*)d_in[2];
  const float* w0     = (const float*)d_in[3];
  const float* root0  = (const float*)d_in[4];
  const float* b0     = (const float*)d_in[5];
  const float* w1     = (const float*)d_in[6];
  const float* root1  = (const float*)d_in[7];
  const float* b1     = (const float*)d_in[8];
  const float* w2     = (const float*)d_in[9];
  const float* root2  = (const float*)d_in[10];
  const float* b2     = (const float*)d_in[11];
  const float* ln_g0  = (const float*)d_in[12];
  const float* ln_b0  = (const float*)d_in[13];
  const float* ln_g1  = (const float*)d_in[14];
  const float* ln_b1  = (const float*)d_in[15];
  const float* ln_g2  = (const float*)d_in[16];
  const float* ln_b2  = (const float*)d_in[17];
  const float* res_w  = (const float*)d_in[18];
  const float* res_b  = (const float*)d_in[19];
  const float* dec_w1 = (const float*)d_in[20];
  const float* dec_b1 = (const float*)d_in[21];
  const float* dec_w2 = (const float*)d_in[22];
  const float* dec_b2 = (const float*)d_in[23];
  const float* dec_w3 = (const float*)d_in[24];
  const float* dec_b3 = (const float*)d_in[25];

  char* ws = (char*)d_ws;
  unsigned char* r8 = (unsigned char*)(ws + 0);        //    800,000 B
  int*   cntR    = (int*)(ws + 800000);                //    600,000 B (memset 0)
  float* agg0    = (float*)(ws + 1400000);             //  1,800,000 B
  int*   bsum    = (int*)(ws + 3200000);               //      1,024 B
  int*   off3    = (int*)(ws + 3201024);               //    600,000 B
  int*   cursor3 = (int*)(ws + 3801024);               //    600,000 B
  float* dinv    = (float*)(ws + 4401024);             //    600,000 B
  int*   sorted  = (int*)(ws + 5001024);               //  3,200,000 B
  unsigned short* hcat = (unsigned short*)(ws + 8201024);   // 25,600,000 B
  unsigned short* pk3  = (unsigned short*)(ws + 33801024);  //     17,408 B
  unsigned short* pkw2 = (unsigned short*)(ws + 33818432);  //      1,024 B
  unsigned short* pkl1 = (unsigned short*)(ws + 33819456);  //     32,768 B
  unsigned short* pkl2 = (unsigned short*)(ws + 33852224);  //     32,768 B
  unsigned short* hb   = (unsigned short*)(ws + 33884992);  //  6,400,000 B (end 40,284,992)

  hipMemsetAsync(cntR, 0, 600000, stream);

  edge_prep<<<(NE + 255) / 256, 256, 0, stream>>>(ei, ea, cntR, r8);
  scanA<<<NB, 256, 0, stream>>>(cntR, bsum);
  scanB<<<1, 256, 0, stream>>>(bsum);
  scanC<<<NB, 256, 0, stream>>>(cntR, bsum, off3, cursor3, dinv);
  scatter_kernel<<<(NE + 255) / 256, 256, 0, stream>>>(ei, r8, cursor3, sorted);
  pack_all<<<3, 256, 0, stream>>>(dec_w1, dec_w2, root1, w1, root2, w2,
                                  pk3, pkw2, pkl1, pkl2);
  agg0_csr<<<(NN + 63) / 64, 256, 0, stream>>>(x, off3, cntR, sorted, agg0);

  const int node0_blocks = (NN / 8 + 3) / 4;          // 8 nodes/wave
  const int agg_blocks   = (NN / 2 + 3) / 4;          // 2 nodes/wave
  const int mfma_blocks  = (NN / 16 + 3) / 4;         // 16 nodes/wave

  node0_kernel<<<node0_blocks, 256, 0, stream>>>(x, agg0, dinv, w0, root0, b0,
                                                 res_w, res_b, ln_g0, ln_b0, hcat, hb);

  agg_csr<<<agg_blocks, 256, 0, stream>>>(hb, hcat, off3, cntR, sorted, dinv);
  node_mfma<<<mfma_blocks, 256, 0, stream>>>(hcat, pkl1, b1, ln_g1, ln_b1, hb, 1);

  agg_csr<<<agg_blocks, 256, 0, stream>>>(hb, hcat, off3, cntR, sorted, dinv);
  node_mfma<<<mfma_blocks, 256, 0, stream>>>(hcat, pkl2, b2, ln_g2, ln_b2, hb, 0);

  decoder_mfma<<<NE / 128, 256, 0, stream>>>(hb, ei, ea, pk3, pkw2, dec_b1,
                                             dec_b2, dec_w3, dec_b3, (float*)d_out);
}

// Round 11
// 381.271 us; speedup vs baseline: 1.2701x; 1.0625x over previous
//
#include <hip/hip_runtime.h>
#include <math.h>

#define NN 50000
#define NE 800000
#define HD 64
#define NB 196  // ceil(50000/256)

typedef float f32x4 __attribute__((ext_vector_type(4)));
typedef float f32x16 __attribute__((ext_vector_type(16)));
typedef short short8 __attribute__((ext_vector_type(8)));

__device__ __forceinline__ float wave_sum(float v) {
  #pragma unroll
  for (int off = 32; off > 0; off >>= 1) v += __shfl_xor(v, off, 64);
  return v;
}

__device__ __forceinline__ unsigned short f2bf_sw(float f) {
  union { float f; unsigned u; } v; v.f = f;
  unsigned r = v.u + 0x7FFF + ((v.u >> 16) & 1);  // RNE
  return (unsigned short)(r >> 16);
}

__device__ __forceinline__ unsigned f2bf_pk(float a, float b) {
#if __has_builtin(__builtin_amdgcn_cvt_pk_bf16_f32)
  typedef __bf16 bf16x2 __attribute__((ext_vector_type(2)));
  union { bf16x2 v; unsigned u; } cv;
  cv.v = __builtin_amdgcn_cvt_pk_bf16_f32(a, b);
  return cv.u;
#else
  return (unsigned)f2bf_sw(a) | ((unsigned)f2bf_sw(b) << 16);
#endif
}
__device__ __forceinline__ unsigned short f2bf(float a) {
#if __has_builtin(__builtin_amdgcn_cvt_pk_bf16_f32)
  return (unsigned short)(f2bf_pk(a, a) & 0xFFFF);
#else
  return f2bf_sw(a);
#endif
}
__device__ __forceinline__ float bf2f(unsigned short b) {
  union { unsigned u; float f; } v; v.u = ((unsigned)b) << 16;
  return v.f;
}

// ---------------- edge prep: histogram + 1-byte relation cache ----------------
__global__ __launch_bounds__(256) void edge_prep(
    const int* __restrict__ ei, const float* __restrict__ ea,
    int* __restrict__ cntR, unsigned char* __restrict__ r8)
{
  int e = blockIdx.x * blockDim.x + threadIdx.x;
  if (e >= NE) return;
  float dist = ea[e * 6];
  const float q1 = log1pf(5000.0f);
  const float q2 = log1pf(10000.0f);
  int r = (dist > q1 ? 1 : 0) + (dist > q2 ? 1 : 0);
  r8[e] = (unsigned char)r;
  int d = ei[NE + e];
  atomicAdd(&cntR[d * 3 + r], 1);
}

// ---------------- CSR build (relation-sorted: runs r=0,1,2 per node) ----------------
__global__ __launch_bounds__(256) void scanA(const int* __restrict__ cntR, int* __restrict__ bsum) {
  __shared__ int sd[256];
  int n = blockIdx.x * 256 + threadIdx.x;
  int deg = 0;
  if (n < NN) deg = cntR[3 * n] + cntR[3 * n + 1] + cntR[3 * n + 2];
  sd[threadIdx.x] = deg;
  __syncthreads();
  #pragma unroll
  for (int s = 128; s > 0; s >>= 1) {
    if (threadIdx.x < s) sd[threadIdx.x] += sd[threadIdx.x + s];
    __syncthreads();
  }
  if (threadIdx.x == 0) bsum[blockIdx.x] = sd[0];
}

__global__ __launch_bounds__(256) void scanB(int* __restrict__ bsum) {
  __shared__ int sd[256];
  int v = (threadIdx.x < NB) ? bsum[threadIdx.x] : 0;
  sd[threadIdx.x] = v;
  __syncthreads();
  for (int s = 1; s < 256; s <<= 1) {
    int t = (threadIdx.x >= s) ? sd[threadIdx.x - s] : 0;
    __syncthreads();
    sd[threadIdx.x] += t;
    __syncthreads();
  }
  if (threadIdx.x < NB) bsum[threadIdx.x] = sd[threadIdx.x] - v;  // exclusive
}

__global__ __launch_bounds__(256) void scanC(
    const int* __restrict__ cntR, const int* __restrict__ bsum,
    int* __restrict__ off3, int* __restrict__ cursor3, float* __restrict__ dinv)
{
  __shared__ int sd[256];
  int n = blockIdx.x * 256 + threadIdx.x;
  int c0 = 0, c1 = 0, c2 = 0;
  if (n < NN) { c0 = cntR[3 * n]; c1 = cntR[3 * n + 1]; c2 = cntR[3 * n + 2]; }
  int deg = c0 + c1 + c2;
  sd[threadIdx.x] = deg;
  __syncthreads();
  for (int s = 1; s < 256; s <<= 1) {
    int t = (threadIdx.x >= s) ? sd[threadIdx.x - s] : 0;
    __syncthreads();
    sd[threadIdx.x] += t;
    __syncthreads();
  }
  if (n < NN) {
    int o = bsum[blockIdx.x] + sd[threadIdx.x] - deg;
    off3[3 * n + 0] = o;           cursor3[3 * n + 0] = o;
    off3[3 * n + 1] = o + c0;      cursor3[3 * n + 1] = o + c0;
    off3[3 * n + 2] = o + c0 + c1; cursor3[3 * n + 2] = o + c0 + c1;
    dinv[3 * n + 0] = 1.0f / (float)(c0 > 1 ? c0 : 1);
    dinv[3 * n + 1] = 1.0f / (float)(c1 > 1 ? c1 : 1);
    dinv[3 * n + 2] = 1.0f / (float)(c2 > 1 ? c2 : 1);
  }
}

// scatter: reads cached 1-byte relation (no ea re-read)
__global__ __launch_bounds__(256) void scatter_kernel(
    const int* __restrict__ ei, const unsigned char* __restrict__ r8,
    int* __restrict__ cursor3, int* __restrict__ sorted)
{
  int e = blockIdx.x * blockDim.x + threadIdx.x;
  if (e >= NE) return;
  int r = r8[e];
  int s = ei[e], d = ei[NE + e];
  int pos = atomicAdd(&cursor3[d * 3 + r], 1);
  sorted[pos] = s;  // src only; relation implied by run
}

// ---- layer-0 aggregation v2: 16 nodes/wave, 4 lanes/node (lane&3 = feature, f==3 idle) -----
__global__ __launch_bounds__(256) void agg0_csr(
    const float* __restrict__ x, const int* __restrict__ off3, const int* __restrict__ cntR,
    const int* __restrict__ sorted, float* __restrict__ agg0)
{
  int wid = (blockIdx.x * blockDim.x + threadIdx.x) >> 6;
  int lane = threadIdx.x & 63;
  int n = wid * 16 + (lane >> 2);
  int f = lane & 3;
  if (n >= NN) return;
  int off = off3[3 * n];
  int c0 = cntR[3 * n], c1 = cntR[3 * n + 1], c2 = cntR[3 * n + 2];
  int c01 = c0 + c1, deg = c01 + c2;
  float a0 = 0.f, a1 = 0.f, a2 = 0.f;
  for (int i = 0; i < deg; i++) {
    int s = sorted[off + i];
    float v = (f < 3) ? x[s * 3 + f] : 0.f;
    if (i < c0) a0 += v; else if (i < c01) a1 += v; else a2 += v;
  }
  if (f < 3) {
    agg0[n * 9 + 0 + f] = a0;
    agg0[n * 9 + 3 + f] = a1;
    agg0[n * 9 + 6 + f] = a2;
  }
}

// ---------------- fused weight packing: block 0 = decoder, blocks 1/2 = node layers ----------
__global__ __launch_bounds__(256) void pack_all(
    const float* __restrict__ W1, const float* __restrict__ W2,
    const float* __restrict__ root1, const float* __restrict__ w1,
    const float* __restrict__ root2, const float* __restrict__ w2,
    unsigned short* __restrict__ pk3, unsigned short* __restrict__ pk2,
    unsigned short* __restrict__ pkl1, unsigned short* __restrict__ pkl2)
{
  if (blockIdx.x == 0) {
    for (int idx = threadIdx.x; idx < 8704; idx += 256) {
      int j = idx & 7, l = (idx >> 3) & 63, t = idx >> 9;
      int k = 16 * t + 8 * (l >> 5) + j;
      int n = l & 31;
      pk3[idx] = (k < 262) ? f2bf(W1[k * 32 + n]) : (unsigned short)0;
    }
    for (int idx = threadIdx.x; idx < 512; idx += 256) {
      int j = idx & 7, l = idx >> 3;
      int k = (l >> 4) * 8 + j, n = l & 15;
      pk2[idx] = f2bf(W2[k * 16 + n]);
    }
  } else {
    const float* root = (blockIdx.x == 1) ? root1 : root2;
    const float* W    = (blockIdx.x == 1) ? w1 : w2;
    unsigned short* pkL = (blockIdx.x == 1) ? pkl1 : pkl2;
    for (int idx = threadIdx.x; idx < 16384; idx += 256) {
      int j = idx & 7, l = (idx >> 3) & 63, nt = (idx >> 9) & 3, t = idx >> 11;
      int k = t * 32 + (l >> 4) * 8 + j;
      int n = nt * 16 + (l & 15);
      float w = (k < 64) ? root[k * 64 + n]
                         : W[((k - 64) >> 6) * 4096 + (k & 63) * 64 + n];
      pkL[idx] = f2bf(w);
    }
  }
}

// ---- CSR aggregation v3: 4 nodes/wave (16 lanes each), uint2 gathers (4 feats/lane),
// ---- inner gather unrolled x2 -> up to 8 loads in flight per wave.
__global__ __launch_bounds__(256) void agg_csr(
    const unsigned short* __restrict__ hb, unsigned short* __restrict__ hcat,
    const int* __restrict__ off3, const int* __restrict__ cntR,
    const int* __restrict__ sorted, const float* __restrict__ dinv)
{
  int wid = (blockIdx.x * blockDim.x + threadIdx.x) >> 6;
  int lane = threadIdx.x & 63;
  int q = lane >> 4;              // quarter 0..3
  int c = lane & 15;              // uint2 index: features 4c .. 4c+3
  int n = wid * 4 + q;            // NN % 4 == 0 -> n < NN when wid valid
  if (wid * 4 >= NN) return;
  const uint2* hb64 = (const uint2*)hb;
  unsigned* hcat32 = (unsigned*)hcat;
  #pragma unroll
  for (int r = 0; r < 3; r++) {
    int st = off3[n * 3 + r], len = cntR[n * 3 + r];
    float a0 = 0.f, a1 = 0.f, a2 = 0.f, a3 = 0.f;
    for (int base = 0; base < len; base += 16) {
      int cnt = len - base; if (cnt > 16) cnt = 16;
      int ent = (c < cnt) ? sorted[st + base + c] : 0;
      int j = 0;
      for (; j + 2 <= cnt; j += 2) {
        int e0 = __shfl(ent, q * 16 + j, 64);
        int e1 = __shfl(ent, q * 16 + j + 1, 64);
        uint2 u0 = hb64[(size_t)e0 * 16 + c];
        uint2 u1 = hb64[(size_t)e1 * 16 + c];
        a0 += bf2f((unsigned short)(u0.x & 0xFFFF)) + bf2f((unsigned short)(u1.x & 0xFFFF));
        a1 += bf2f((unsigned short)(u0.x >> 16))    + bf2f((unsigned short)(u1.x >> 16));
        a2 += bf2f((unsigned short)(u0.y & 0xFFFF)) + bf2f((unsigned short)(u1.y & 0xFFFF));
        a3 += bf2f((unsigned short)(u0.y >> 16))    + bf2f((unsigned short)(u1.y >> 16));
      }
      if (j < cnt) {
        int e0 = __shfl(ent, q * 16 + j, 64);
        uint2 u0 = hb64[(size_t)e0 * 16 + c];
        a0 += bf2f((unsigned short)(u0.x & 0xFFFF));
        a1 += bf2f((unsigned short)(u0.x >> 16));
        a2 += bf2f((unsigned short)(u0.y & 0xFFFF));
        a3 += bf2f((unsigned short)(u0.y >> 16));
      }
    }
    float dv = dinv[n * 3 + r];
    hcat32[(size_t)n * 128 + 32 + r * 32 + 2 * c]     = f2bf_pk(a0 * dv, a1 * dv);
    hcat32[(size_t)n * 128 + 32 + r * 32 + 2 * c + 1] = f2bf_pk(a2 * dv, a3 * dv);
  }
}

// ---------------- layer 0 node update (IN=3) + relu + residual + LN; bf16 outputs only -------
__global__ __launch_bounds__(256) void node0_kernel(
    const float* __restrict__ x, const float* __restrict__ agg0, const float* __restrict__ dinv,
    const float* __restrict__ w0, const float* __restrict__ root0, const float* __restrict__ b0,
    const float* __restrict__ res_w, const float* __restrict__ res_b,
    const float* __restrict__ g, const float* __restrict__ bb,
    unsigned short* __restrict__ hcat, unsigned short* __restrict__ hb)
{
  int wid = __builtin_amdgcn_readfirstlane((int)((blockIdx.x * blockDim.x + threadIdx.x) >> 6));
  int lane = threadIdx.x & 63;
  int n0 = wid * 8;
  if (n0 >= NN) return;
  float wr[3], ww[9], wres[3];
  #pragma unroll
  for (int i = 0; i < 3; i++) { wr[i] = root0[i * HD + lane]; wres[i] = res_w[i * HD + lane]; }
  #pragma unroll
  for (int i = 0; i < 9; i++) ww[i] = w0[i * HD + lane];
  float vb = b0[lane], vrb = res_b[lane], vg = g[lane], vbb = bb[lane];
  #pragma unroll
  for (int k = 0; k < 8; k++) {
    int nk = n0 + k;
    float xv[3];
    #pragma unroll
    for (int i = 0; i < 3; i++) xv[i] = x[nk * 3 + i];
    float v = vb;
    #pragma unroll
    for (int i = 0; i < 3; i++) v = fmaf(xv[i], wr[i], v);
    #pragma unroll
    for (int r = 0; r < 3; r++) {
      float s = 0.f;
      #pragma unroll
      for (int i = 0; i < 3; i++) s = fmaf(agg0[nk * 9 + r * 3 + i], ww[r * 3 + i], s);
      v = fmaf(dinv[nk * 3 + r], s, v);
    }
    v = fmaxf(v, 0.f);
    float res = vrb;
    #pragma unroll
    for (int i = 0; i < 3; i++) res = fmaf(xv[i], wres[i], res);
    float t = v + res;
    float mu = wave_sum(t) * 0.015625f;
    float dt = t - mu;
    float var = wave_sum(dt * dt) * 0.015625f;
    float o = dt * rsqrtf(var + 1e-5f) * vg + vbb;
    unsigned short ob = f2bf(o);
    hcat[(size_t)nk * 256 + lane] = ob;
    hb[(size_t)nk * HD + lane] = ob;
  }
}

// ---- node update as MFMA GEMM; residual read as bf16 from hcat cols 0..63 (pre-overwrite) ---
__global__ __launch_bounds__(256) void node_mfma(
    unsigned short* __restrict__ hcat, const unsigned short* __restrict__ pkL,
    const float* __restrict__ bias, const float* __restrict__ g, const float* __restrict__ bb,
    unsigned short* __restrict__ hb, int write_next)
{
  int wid = (blockIdx.x * blockDim.x + threadIdx.x) >> 6;
  int lane = threadIdx.x & 63;
  int n0 = wid * 16;
  if (n0 >= NN) return;
  int m = lane & 15, gq = lane >> 4;

  const short8* Ap = (const short8*)(hcat + (size_t)(n0 + m) * 256 + gq * 8);
  const short8* Bp = (const short8*)pkL;
  f32x4 acc[4];
  #pragma unroll
  for (int nt = 0; nt < 4; nt++) acc[nt] = (f32x4){0.f, 0.f, 0.f, 0.f};
  #pragma unroll
  for (int t = 0; t < 8; t++) {
    short8 a = Ap[t * 4];
    #pragma unroll
    for (int nt = 0; nt < 4; nt++)
      acc[nt] = __builtin_amdgcn_mfma_f32_16x16x32_bf16(a, Bp[(t * 4 + nt) * 64 + lane], acc[nt], 0, 0, 0);
  }

  float bias_v[4], g_v[4], bb_v[4];
  #pragma unroll
  for (int nt = 0; nt < 4; nt++) {
    bias_v[nt] = bias[nt * 16 + m];
    g_v[nt] = g[nt * 16 + m];
    bb_v[nt] = bb[nt * 16 + m];
  }
  #pragma unroll
  for (int r = 0; r < 4; r++) {
    int node = n0 + gq * 4 + r;   // C layout: row = quad*4 + reg
    float tv[4], s = 0.f;
    #pragma unroll
    for (int nt = 0; nt < 4; nt++) {
      float res = bf2f(hcat[(size_t)node * 256 + nt * 16 + m]);
      float v = fmaxf(acc[nt][r] + bias_v[nt], 0.f) + res;
      tv[nt] = v; s += v;
    }
    #pragma unroll
    for (int o = 1; o < 16; o <<= 1) s += __shfl_xor(s, o, 64);
    float mu = s * 0.015625f;
    float s2 = 0.f;
    #pragma unroll
    for (int nt = 0; nt < 4; nt++) { float dd = tv[nt] - mu; s2 += dd * dd; }
    #pragma unroll
    for (int o = 1; o < 16; o <<= 1) s2 += __shfl_xor(s2, o, 64);
    float rstd = rsqrtf(s2 * 0.015625f + 1e-5f);
    #pragma unroll
    for (int nt = 0; nt < 4; nt++) {
      float o = (tv[nt] - mu) * rstd * g_v[nt] + bb_v[nt];
      unsigned short ob = f2bf(o);
      hb[(size_t)node * HD + nt * 16 + m] = ob;
      if (write_next) hcat[(size_t)node * 256 + nt * 16 + m] = ob;
    }
  }
}

// ---------------- decoder v3: 32 edges/wave, 32x32x16 MFMA, ea folded into K ----------------
__global__ __launch_bounds__(256) void decoder_mfma(
    const unsigned short* __restrict__ hb, const int* __restrict__ ei, const float* __restrict__ ea,
    const unsigned short* __restrict__ pk3, const unsigned short* __restrict__ pk2,
    const float* __restrict__ B1, const float* __restrict__ B2,
    const float* __restrict__ W3, const float* __restrict__ B3,
    float* __restrict__ out)
{
  __shared__ float lds[4 * 32 * 33];
  int wv = threadIdx.x >> 6;
  int lane = threadIdx.x & 63;
  int e0 = (blockIdx.x * 4 + wv) * 32;
  int r = lane & 31, u = lane >> 5;

  int s = ei[e0 + r], d = ei[NE + e0 + r];
  const unsigned short* ps = hb + (size_t)s * HD + u * 8;
  const unsigned short* pq = hb + (size_t)d * HD + u * 8;
  short8 hs[4], hd[4];
  #pragma unroll
  for (int t = 0; t < 4; t++) {
    hs[t] = *(const short8*)(ps + t * 16);
    hd[t] = *(const short8*)(pq + t * 16);
  }

  union u8 { short8 s8; unsigned w[4]; };
  u8 ad[4], pd[4];
  #pragma unroll
  for (int t = 0; t < 4; t++) {
    #pragma unroll
    for (int j2 = 0; j2 < 4; j2++) {
      float a0 = bf2f((unsigned short)hs[t][2 * j2]),     b0 = bf2f((unsigned short)hd[t][2 * j2]);
      float a1 = bf2f((unsigned short)hs[t][2 * j2 + 1]), b1 = bf2f((unsigned short)hd[t][2 * j2 + 1]);
      ad[t].w[j2] = f2bf_pk(fabsf(a0 - b0), fabsf(a1 - b1));
      pd[t].w[j2] = f2bf_pk(a0 * b0, a1 * b1);
    }
  }

  u8 aea;
  aea.w[0] = 0; aea.w[1] = 0; aea.w[2] = 0; aea.w[3] = 0;
  if (u == 0) {
    const float* er = ea + (size_t)(e0 + r) * 6;
    float2 e01 = *(const float2*)(er);
    float2 e23 = *(const float2*)(er + 2);
    float2 e45 = *(const float2*)(er + 4);
    aea.w[0] = f2bf_pk(e01.x, e01.y);
    aea.w[1] = f2bf_pk(e23.x, e23.y);
    aea.w[2] = f2bf_pk(e45.x, e45.y);
  }

  const short8* Bp = (const short8*)pk3;
  f32x16 acc = {0.f, 0.f, 0.f, 0.f, 0.f, 0.f, 0.f, 0.f,
                0.f, 0.f, 0.f, 0.f, 0.f, 0.f, 0.f, 0.f};
  #pragma unroll
  for (int t = 0; t < 4; t++)
    acc = __builtin_amdgcn_mfma_f32_32x32x16_bf16(hs[t], Bp[t * 64 + lane], acc, 0, 0, 0);
  #pragma unroll
  for (int t = 0; t < 4; t++)
    acc = __builtin_amdgcn_mfma_f32_32x32x16_bf16(hd[t], Bp[(4 + t) * 64 + lane], acc, 0, 0, 0);
  #pragma unroll
  for (int t = 0; t < 4; t++)
    acc = __builtin_amdgcn_mfma_f32_32x32x16_bf16(ad[t].s8, Bp[(8 + t) * 64 + lane], acc, 0, 0, 0);
  #pragma unroll
  for (int t = 0; t < 4; t++)
    acc = __builtin_amdgcn_mfma_f32_32x32x16_bf16(pd[t].s8, Bp[(12 + t) * 64 + lane], acc, 0, 0, 0);
  acc = __builtin_amdgcn_mfma_f32_32x32x16_bf16(aea.s8, Bp[16 * 64 + lane], acc, 0, 0, 0);

  float* Z = lds + wv * 1056;
  float b1v = B1[r];
  #pragma unroll
  for (int i = 0; i < 16; i++) {
    int row = (i & 3) + 8 * (i >> 2) + 4 * u;
    Z[r * 33 + row] = fmaxf(acc[i] + b1v, 0.f);
  }

  int m = lane & 15, g = lane >> 4;
  float bias2 = B2[m];
  float w3v = W3[m];
  #pragma unroll
  for (int q = 0; q < 2; q++) {
    u8 A2;
    #pragma unroll
    for (int j2 = 0; j2 < 4; j2++)
      A2.w[j2] = f2bf_pk(Z[(g * 8 + 2 * j2) * 33 + q * 16 + m],
                         Z[(g * 8 + 2 * j2 + 1) * 33 + q * 16 + m]);
    f32x4 acc2 = {0.f, 0.f, 0.f, 0.f};
    acc2 = __builtin_amdgcn_mfma_f32_16x16x32_bf16(A2.s8, ((const short8*)pk2)[lane], acc2, 0, 0, 0);

    float t0 = fmaxf(acc2[0] + bias2, 0.f) * w3v;
    float t1 = fmaxf(acc2[1] + bias2, 0.f) * w3v;
    float t2 = fmaxf(acc2[2] + bias2, 0.f) * w3v;
    float t3 = fmaxf(acc2[3] + bias2, 0.f) * w3v;
    #pragma unroll
    for (int off = 1; off < 16; off <<= 1) {
      t0 += __shfl_xor(t0, off, 64);
      t1 += __shfl_xor(t1, off, 64);
      t2 += __shfl_xor(t2, off, 64);
      t3 += __shfl_xor(t3, off, 64);
    }
    if (m < 4) {
      float val = (m == 0) ? t0 : (m == 1) ? t1 : (m == 2) ? t2 : t3;
      out[e0 + q * 16 + g * 4 + m] = val + B3[0];
    }
  }
}

extern "C" void kernel_launch(void* const* d_in, const int* in_sizes, int n_in,
                              void* d_out, int out_size, void* d_ws, size_t ws_size,
                              hipStream_t stream) {
  const float* x      = (const float*)d_in[0];
  const int*   ei     = (const int*)d_in[1];
  const float* ea     = (const float*)d_in[2];
  const float* w0     = (const float*)d_in[3];
  const float* root0  = (const float*)d_in[4];
  const float* b0     = (const float*)d_in[5];
  const float* w1     = (const float*)d_in[6];
  const float* root1  = (const float*)d_in[7];
  const float* b1     = (const float*)d_in[8];
  const float* w2     = (const float*)d_in[9];
  const float* root2  = (const float*)d_in[10];
  const float* b2     = (const float*)d_in[11];
  const float* ln_g0  = (const float*)d_in[12];
  const float* ln_b0  = (const float*)d_in[13];
  const float* ln_g1  = (const float*)d_in[14];
  const float* ln_b1  = (const float*)d_in[15];
  const float* ln_g2  = (const float*)d_in[16];
  const float* ln_b2  = (const float*)d_in[17];
  const float* res_w  = (const float*)d_in[18];
  const float* res_b  = (const float*)d_in[19];
  const float* dec_w1 = (const float*)d_in[20];
  const float* dec_b1 = (const float*)d_in[21];
  const float* dec_w2 = (const float*)d_in[22];
  const float* dec_b2 = (const float*)d_in[23];
  const float* dec_w3 = (const float*)d_in[24];
  const float* dec_b3 = (const float*)d_in[25];

  char* ws = (char*)d_ws;
  unsigned char* r8 = (unsigned char*)(ws + 0);        //    800,000 B
  int*   cntR    = (int*)(ws + 800000);                //    600,000 B (memset 0)
  float* agg0    = (float*)(ws + 1400000);             //  1,800,000 B
  int*   bsum    = (int*)(ws + 3200000);               //      1,024 B
  int*   off3    = (int*)(ws + 3201024);               //    600,000 B
  int*   cursor3 = (int*)(ws + 3801024);               //    600,000 B
  float* dinv    = (float*)(ws + 4401024);             //    600,000 B
  int*   sorted  = (int*)(ws + 5001024);               //  3,200,000 B
  unsigned short* hcat = (unsigned short*)(ws + 8201024);   // 25,600,000 B
  unsigned short* pk3  = (unsigned short*)(ws + 33801024);  //     17,408 B
  unsigned short* pkw2 = (unsigned short*)(ws + 33818432);  //      1,024 B
  unsigned short* pkl1 = (unsigned short*)(ws + 33819456);  //     32,768 B
  unsigned short* pkl2 = (unsigned short*)(ws + 33852224);  //     32,768 B
  unsigned short* hb   = (unsigned short*)(ws + 33884992);  //  6,400,000 B (end 40,284,992)

  hipMemsetAsync(cntR, 0, 600000, stream);

  edge_prep<<<(NE + 255) / 256, 256, 0, stream>>>(ei, ea, cntR, r8);
  scanA<<<NB, 256, 0, stream>>>(cntR, bsum);
  scanB<<<1, 256, 0, stream>>>(bsum);
  scanC<<<NB, 256, 0, stream>>>(cntR, bsum, off3, cursor3, dinv);
  scatter_kernel<<<(NE + 255) / 256, 256, 0, stream>>>(ei, r8, cursor3, sorted);
  pack_all<<<3, 256, 0, stream>>>(dec_w1, dec_w2, root1, w1, root2, w2,
                                  pk3, pkw2, pkl1, pkl2);
  agg0_csr<<<(NN + 63) / 64, 256, 0, stream>>>(x, off3, cntR, sorted, agg0);

  const int node0_blocks = (NN / 8 + 3) / 4;          // 8 nodes/wave
  const int agg_blocks   = (NN / 4 + 3) / 4;          // 4 nodes/wave
  const int mfma_blocks  = (NN / 16 + 3) / 4;         // 16 nodes/wave

  node0_kernel<<<node0_blocks, 256, 0, stream>>>(x, agg0, dinv, w0, root0, b0,
                                                 res_w, res_b, ln_g0, ln_b0, hcat, hb);

  agg_csr<<<agg_blocks, 256, 0, stream>>>(hb, hcat, off3, cntR, sorted, dinv);
  node_mfma<<<mfma_blocks, 256, 0, stream>>>(hcat, pkl1, b1, ln_g1, ln_b1, hb, 1);

  agg_csr<<<agg_blocks, 256, 0, stream>>>(hb, hcat, off3, cntR, sorted, dinv);
  node_mfma<<<mfma_blocks, 256, 0, stream>>>(hcat, pkl2, b2, ln_g2, ln_b2, hb, 0);

  decoder_mfma<<<NE / 128, 256, 0, stream>>>(hb, ei, ea, pk3, pkw2, dec_b1,
                                             dec_b2, dec_w3, dec_b3, (float*)d_out);
}

// Round 12
// 362.841 us; speedup vs baseline: 1.3346x; 1.0508x over previous
//
#include <hip/hip_runtime.h>
#include <math.h>

#define NN 50000
#define NE 800000
#define HD 64
#define NB 196  // ceil(50000/256)

typedef float f32x4 __attribute__((ext_vector_type(4)));
typedef float f32x16 __attribute__((ext_vector_type(16)));
typedef short short8 __attribute__((ext_vector_type(8)));

__device__ __forceinline__ float wave_sum(float v) {
  #pragma unroll
  for (int off = 32; off > 0; off >>= 1) v += __shfl_xor(v, off, 64);
  return v;
}

__device__ __forceinline__ unsigned short f2bf_sw(float f) {
  union { float f; unsigned u; } v; v.f = f;
  unsigned r = v.u + 0x7FFF + ((v.u >> 16) & 1);  // RNE
  return (unsigned short)(r >> 16);
}

__device__ __forceinline__ unsigned f2bf_pk(float a, float b) {
#if __has_builtin(__builtin_amdgcn_cvt_pk_bf16_f32)
  typedef __bf16 bf16x2 __attribute__((ext_vector_type(2)));
  union { bf16x2 v; unsigned u; } cv;
  cv.v = __builtin_amdgcn_cvt_pk_bf16_f32(a, b);
  return cv.u;
#else
  return (unsigned)f2bf_sw(a) | ((unsigned)f2bf_sw(b) << 16);
#endif
}
__device__ __forceinline__ unsigned short f2bf(float a) {
#if __has_builtin(__builtin_amdgcn_cvt_pk_bf16_f32)
  return (unsigned short)(f2bf_pk(a, a) & 0xFFFF);
#else
  return f2bf_sw(a);
#endif
}
__device__ __forceinline__ float bf2f(unsigned short b) {
  union { unsigned u; float f; } v; v.u = ((unsigned)b) << 16;
  return v.f;
}

// ---------------- edge prep: histogram + 1-byte relation cache ----------------
__global__ __launch_bounds__(256) void edge_prep(
    const int* __restrict__ ei, const float* __restrict__ ea,
    int* __restrict__ cntR, unsigned char* __restrict__ r8)
{
  int e = blockIdx.x * blockDim.x + threadIdx.x;
  if (e >= NE) return;
  float dist = ea[e * 6];
  const float q1 = log1pf(5000.0f);
  const float q2 = log1pf(10000.0f);
  int r = (dist > q1 ? 1 : 0) + (dist > q2 ? 1 : 0);
  r8[e] = (unsigned char)r;
  int d = ei[NE + e];
  atomicAdd(&cntR[d * 3 + r], 1);
}

// ---------------- CSR build (relation-sorted: runs r=0,1,2 per node) ----------------
__global__ __launch_bounds__(256) void scanA(const int* __restrict__ cntR, int* __restrict__ bsum) {
  __shared__ int sd[256];
  int n = blockIdx.x * 256 + threadIdx.x;
  int deg = 0;
  if (n < NN) deg = cntR[3 * n] + cntR[3 * n + 1] + cntR[3 * n + 2];
  sd[threadIdx.x] = deg;
  __syncthreads();
  #pragma unroll
  for (int s = 128; s > 0; s >>= 1) {
    if (threadIdx.x < s) sd[threadIdx.x] += sd[threadIdx.x + s];
    __syncthreads();
  }
  if (threadIdx.x == 0) bsum[blockIdx.x] = sd[0];
}

__global__ __launch_bounds__(256) void scanB(int* __restrict__ bsum) {
  __shared__ int sd[256];
  int v = (threadIdx.x < NB) ? bsum[threadIdx.x] : 0;
  sd[threadIdx.x] = v;
  __syncthreads();
  for (int s = 1; s < 256; s <<= 1) {
    int t = (threadIdx.x >= s) ? sd[threadIdx.x - s] : 0;
    __syncthreads();
    sd[threadIdx.x] += t;
    __syncthreads();
  }
  if (threadIdx.x < NB) bsum[threadIdx.x] = sd[threadIdx.x] - v;  // exclusive
}

__global__ __launch_bounds__(256) void scanC(
    const int* __restrict__ cntR, const int* __restrict__ bsum,
    int* __restrict__ off3, int* __restrict__ cursor3, float* __restrict__ dinv)
{
  __shared__ int sd[256];
  int n = blockIdx.x * 256 + threadIdx.x;
  int c0 = 0, c1 = 0, c2 = 0;
  if (n < NN) { c0 = cntR[3 * n]; c1 = cntR[3 * n + 1]; c2 = cntR[3 * n + 2]; }
  int deg = c0 + c1 + c2;
  sd[threadIdx.x] = deg;
  __syncthreads();
  for (int s = 1; s < 256; s <<= 1) {
    int t = (threadIdx.x >= s) ? sd[threadIdx.x - s] : 0;
    __syncthreads();
    sd[threadIdx.x] += t;
    __syncthreads();
  }
  if (n < NN) {
    int o = bsum[blockIdx.x] + sd[threadIdx.x] - deg;
    off3[3 * n + 0] = o;           cursor3[3 * n + 0] = o;
    off3[3 * n + 1] = o + c0;      cursor3[3 * n + 1] = o + c0;
    off3[3 * n + 2] = o + c0 + c1; cursor3[3 * n + 2] = o + c0 + c1;
    dinv[3 * n + 0] = 1.0f / (float)(c0 > 1 ? c0 : 1);
    dinv[3 * n + 1] = 1.0f / (float)(c1 > 1 ? c1 : 1);
    dinv[3 * n + 2] = 1.0f / (float)(c2 > 1 ? c2 : 1);
  }
}

// scatter: ushort payload (src < 65536) -> half the write-through traffic
__global__ __launch_bounds__(256) void scatter_kernel(
    const int* __restrict__ ei, const unsigned char* __restrict__ r8,
    int* __restrict__ cursor3, unsigned short* __restrict__ sorted)
{
  int e = blockIdx.x * blockDim.x + threadIdx.x;
  if (e >= NE) return;
  int r = r8[e];
  int s = ei[e], d = ei[NE + e];
  int pos = atomicAdd(&cursor3[d * 3 + r], 1);
  sorted[pos] = (unsigned short)s;
}

// ---- fused: blocks 0-2 pack weights; blocks 3+ do layer-0 aggregation (16 nodes/wave) ------
__global__ __launch_bounds__(256) void agg0_pack(
    const float* __restrict__ x, const int* __restrict__ off3, const int* __restrict__ cntR,
    const unsigned short* __restrict__ sorted, float* __restrict__ agg0,
    const float* __restrict__ W1, const float* __restrict__ W2,
    const float* __restrict__ root1, const float* __restrict__ w1,
    const float* __restrict__ root2, const float* __restrict__ w2,
    unsigned short* __restrict__ pk3, unsigned short* __restrict__ pk2,
    unsigned short* __restrict__ pkl1, unsigned short* __restrict__ pkl2)
{
  if (blockIdx.x < 3) {
    if (blockIdx.x == 0) {
      for (int idx = threadIdx.x; idx < 8704; idx += 256) {
        int j = idx & 7, l = (idx >> 3) & 63, t = idx >> 9;
        int k = 16 * t + 8 * (l >> 5) + j;
        int n = l & 31;
        pk3[idx] = (k < 262) ? f2bf(W1[k * 32 + n]) : (unsigned short)0;
      }
      for (int idx = threadIdx.x; idx < 512; idx += 256) {
        int j = idx & 7, l = idx >> 3;
        int k = (l >> 4) * 8 + j, n = l & 15;
        pk2[idx] = f2bf(W2[k * 16 + n]);
      }
    } else {
      const float* root = (blockIdx.x == 1) ? root1 : root2;
      const float* W    = (blockIdx.x == 1) ? w1 : w2;
      unsigned short* pkL = (blockIdx.x == 1) ? pkl1 : pkl2;
      for (int idx = threadIdx.x; idx < 16384; idx += 256) {
        int j = idx & 7, l = (idx >> 3) & 63, nt = (idx >> 9) & 3, t = idx >> 11;
        int k = t * 32 + (l >> 4) * 8 + j;
        int n = nt * 16 + (l & 15);
        float w = (k < 64) ? root[k * 64 + n]
                           : W[((k - 64) >> 6) * 4096 + (k & 63) * 64 + n];
        pkL[idx] = f2bf(w);
      }
    }
    return;
  }
  int wid = ((blockIdx.x - 3) * blockDim.x + threadIdx.x) >> 6;
  int lane = threadIdx.x & 63;
  int n = wid * 16 + (lane >> 2);
  int f = lane & 3;
  if (n >= NN) return;
  int off = off3[3 * n];
  int c0 = cntR[3 * n], c1 = cntR[3 * n + 1], c2 = cntR[3 * n + 2];
  int c01 = c0 + c1, deg = c01 + c2;
  float a0 = 0.f, a1 = 0.f, a2 = 0.f;
  for (int i = 0; i < deg; i++) {
    int s = sorted[off + i];
    float v = (f < 3) ? x[s * 3 + f] : 0.f;
    if (i < c0) a0 += v; else if (i < c01) a1 += v; else a2 += v;
  }
  if (f < 3) {
    agg0[n * 9 + 0 + f] = a0;
    agg0[n * 9 + 3 + f] = a1;
    agg0[n * 9 + 6 + f] = a2;
  }
}

// ---- CSR aggregation v3: 4 nodes/wave (16 lanes each), uint2 gathers, inner unroll x2 -------
__global__ __launch_bounds__(256) void agg_csr(
    const unsigned short* __restrict__ hb, unsigned short* __restrict__ hcat,
    const int* __restrict__ off3, const int* __restrict__ cntR,
    const unsigned short* __restrict__ sorted, const float* __restrict__ dinv)
{
  int wid = (blockIdx.x * blockDim.x + threadIdx.x) >> 6;
  int lane = threadIdx.x & 63;
  int q = lane >> 4;              // quarter 0..3
  int c = lane & 15;              // uint2 index: features 4c .. 4c+3
  int n = wid * 4 + q;
  if (wid * 4 >= NN) return;
  const uint2* hb64 = (const uint2*)hb;
  unsigned* hcat32 = (unsigned*)hcat;
  #pragma unroll
  for (int r = 0; r < 3; r++) {
    int st = off3[n * 3 + r], len = cntR[n * 3 + r];
    float a0 = 0.f, a1 = 0.f, a2 = 0.f, a3 = 0.f;
    for (int base = 0; base < len; base += 16) {
      int cnt = len - base; if (cnt > 16) cnt = 16;
      int ent = (c < cnt) ? sorted[st + base + c] : 0;
      int j = 0;
      for (; j + 2 <= cnt; j += 2) {
        int e0 = __shfl(ent, q * 16 + j, 64);
        int e1 = __shfl(ent, q * 16 + j + 1, 64);
        uint2 u0 = hb64[(size_t)e0 * 16 + c];
        uint2 u1 = hb64[(size_t)e1 * 16 + c];
        a0 += bf2f((unsigned short)(u0.x & 0xFFFF)) + bf2f((unsigned short)(u1.x & 0xFFFF));
        a1 += bf2f((unsigned short)(u0.x >> 16))    + bf2f((unsigned short)(u1.x >> 16));
        a2 += bf2f((unsigned short)(u0.y & 0xFFFF)) + bf2f((unsigned short)(u1.y & 0xFFFF));
        a3 += bf2f((unsigned short)(u0.y >> 16))    + bf2f((unsigned short)(u1.y >> 16));
      }
      if (j < cnt) {
        int e0 = __shfl(ent, q * 16 + j, 64);
        uint2 u0 = hb64[(size_t)e0 * 16 + c];
        a0 += bf2f((unsigned short)(u0.x & 0xFFFF));
        a1 += bf2f((unsigned short)(u0.x >> 16));
        a2 += bf2f((unsigned short)(u0.y & 0xFFFF));
        a3 += bf2f((unsigned short)(u0.y >> 16));
      }
    }
    float dv = dinv[n * 3 + r];
    hcat32[(size_t)n * 128 + 32 + r * 32 + 2 * c]     = f2bf_pk(a0 * dv, a1 * dv);
    hcat32[(size_t)n * 128 + 32 + r * 32 + 2 * c + 1] = f2bf_pk(a2 * dv, a3 * dv);
  }
}

// ---------------- layer 0 node update (IN=3) + relu + residual + LN; bf16 outputs only -------
__global__ __launch_bounds__(256) void node0_kernel(
    const float* __restrict__ x, const float* __restrict__ agg0, const float* __restrict__ dinv,
    const float* __restrict__ w0, const float* __restrict__ root0, const float* __restrict__ b0,
    const float* __restrict__ res_w, const float* __restrict__ res_b,
    const float* __restrict__ g, const float* __restrict__ bb,
    unsigned short* __restrict__ hcat, unsigned short* __restrict__ hb)
{
  int wid = __builtin_amdgcn_readfirstlane((int)((blockIdx.x * blockDim.x + threadIdx.x) >> 6));
  int lane = threadIdx.x & 63;
  int n0 = wid * 8;
  if (n0 >= NN) return;
  float wr[3], ww[9], wres[3];
  #pragma unroll
  for (int i = 0; i < 3; i++) { wr[i] = root0[i * HD + lane]; wres[i] = res_w[i * HD + lane]; }
  #pragma unroll
  for (int i = 0; i < 9; i++) ww[i] = w0[i * HD + lane];
  float vb = b0[lane], vrb = res_b[lane], vg = g[lane], vbb = bb[lane];
  #pragma unroll
  for (int k = 0; k < 8; k++) {
    int nk = n0 + k;
    float xv[3];
    #pragma unroll
    for (int i = 0; i < 3; i++) xv[i] = x[nk * 3 + i];
    float v = vb;
    #pragma unroll
    for (int i = 0; i < 3; i++) v = fmaf(xv[i], wr[i], v);
    #pragma unroll
    for (int r = 0; r < 3; r++) {
      float s = 0.f;
      #pragma unroll
      for (int i = 0; i < 3; i++) s = fmaf(agg0[nk * 9 + r * 3 + i], ww[r * 3 + i], s);
      v = fmaf(dinv[nk * 3 + r], s, v);
    }
    v = fmaxf(v, 0.f);
    float res = vrb;
    #pragma unroll
    for (int i = 0; i < 3; i++) res = fmaf(xv[i], wres[i], res);
    float t = v + res;
    float mu = wave_sum(t) * 0.015625f;
    float dt = t - mu;
    float var = wave_sum(dt * dt) * 0.015625f;
    float o = dt * rsqrtf(var + 1e-5f) * vg + vbb;
    unsigned short ob = f2bf(o);
    hcat[(size_t)nk * 256 + lane] = ob;
    hb[(size_t)nk * HD + lane] = ob;
  }
}

// ---- node update as MFMA GEMM; residual read as bf16 from hcat cols 0..63 (pre-overwrite) ---
__global__ __launch_bounds__(256) void node_mfma(
    unsigned short* __restrict__ hcat, const unsigned short* __restrict__ pkL,
    const float* __restrict__ bias, const float* __restrict__ g, const float* __restrict__ bb,
    unsigned short* __restrict__ hb, int write_next)
{
  int wid = (blockIdx.x * blockDim.x + threadIdx.x) >> 6;
  int lane = threadIdx.x & 63;
  int n0 = wid * 16;
  if (n0 >= NN) return;
  int m = lane & 15, gq = lane >> 4;

  const short8* Ap = (const short8*)(hcat + (size_t)(n0 + m) * 256 + gq * 8);
  const short8* Bp = (const short8*)pkL;
  f32x4 acc[4];
  #pragma unroll
  for (int nt = 0; nt < 4; nt++) acc[nt] = (f32x4){0.f, 0.f, 0.f, 0.f};
  #pragma unroll
  for (int t = 0; t < 8; t++) {
    short8 a = Ap[t * 4];
    #pragma unroll
    for (int nt = 0; nt < 4; nt++)
      acc[nt] = __builtin_amdgcn_mfma_f32_16x16x32_bf16(a, Bp[(t * 4 + nt) * 64 + lane], acc[nt], 0, 0, 0);
  }

  float bias_v[4], g_v[4], bb_v[4];
  #pragma unroll
  for (int nt = 0; nt < 4; nt++) {
    bias_v[nt] = bias[nt * 16 + m];
    g_v[nt] = g[nt * 16 + m];
    bb_v[nt] = bb[nt * 16 + m];
  }
  #pragma unroll
  for (int r = 0; r < 4; r++) {
    int node = n0 + gq * 4 + r;   // C layout: row = quad*4 + reg
    float tv[4], s = 0.f;
    #pragma unroll
    for (int nt = 0; nt < 4; nt++) {
      float res = bf2f(hcat[(size_t)node * 256 + nt * 16 + m]);
      float v = fmaxf(acc[nt][r] + bias_v[nt], 0.f) + res;
      tv[nt] = v; s += v;
    }
    #pragma unroll
    for (int o = 1; o < 16; o <<= 1) s += __shfl_xor(s, o, 64);
    float mu = s * 0.015625f;
    float s2 = 0.f;
    #pragma unroll
    for (int nt = 0; nt < 4; nt++) { float dd = tv[nt] - mu; s2 += dd * dd; }
    #pragma unroll
    for (int o = 1; o < 16; o <<= 1) s2 += __shfl_xor(s2, o, 64);
    float rstd = rsqrtf(s2 * 0.015625f + 1e-5f);
    #pragma unroll
    for (int nt = 0; nt < 4; nt++) {
      float o = (tv[nt] - mu) * rstd * g_v[nt] + bb_v[nt];
      unsigned short ob = f2bf(o);
      hb[(size_t)node * HD + nt * 16 + m] = ob;
      if (write_next) hcat[(size_t)node * 256 + nt * 16 + m] = ob;
    }
  }
}

// ---------------- decoder v3: 32 edges/wave, 32x32x16 MFMA, ea folded into K ----------------
__global__ __launch_bounds__(256) void decoder_mfma(
    const unsigned short* __restrict__ hb, const int* __restrict__ ei, const float* __restrict__ ea,
    const unsigned short* __restrict__ pk3, const unsigned short* __restrict__ pk2,
    const float* __restrict__ B1, const float* __restrict__ B2,
    const float* __restrict__ W3, const float* __restrict__ B3,
    float* __restrict__ out)
{
  __shared__ float lds[4 * 32 * 33];
  int wv = threadIdx.x >> 6;
  int lane = threadIdx.x & 63;
  int e0 = (blockIdx.x * 4 + wv) * 32;
  int r = lane & 31, u = lane >> 5;

  int s = ei[e0 + r], d = ei[NE + e0 + r];
  const unsigned short* ps = hb + (size_t)s * HD + u * 8;
  const unsigned short* pq = hb + (size_t)d * HD + u * 8;
  short8 hs[4], hd[4];
  #pragma unroll
  for (int t = 0; t < 4; t++) {
    hs[t] = *(const short8*)(ps + t * 16);
    hd[t] = *(const short8*)(pq + t * 16);
  }

  union u8 { short8 s8; unsigned w[4]; };
  u8 ad[4], pd[4];
  #pragma unroll
  for (int t = 0; t < 4; t++) {
    #pragma unroll
    for (int j2 = 0; j2 < 4; j2++) {
      float a0 = bf2f((unsigned short)hs[t][2 * j2]),     b0 = bf2f((unsigned short)hd[t][2 * j2]);
      float a1 = bf2f((unsigned short)hs[t][2 * j2 + 1]), b1 = bf2f((unsigned short)hd[t][2 * j2 + 1]);
      ad[t].w[j2] = f2bf_pk(fabsf(a0 - b0), fabsf(a1 - b1));
      pd[t].w[j2] = f2bf_pk(a0 * b0, a1 * b1);
    }
  }

  u8 aea;
  aea.w[0] = 0; aea.w[1] = 0; aea.w[2] = 0; aea.w[3] = 0;
  if (u == 0) {
    const float* er = ea + (size_t)(e0 + r) * 6;
    float2 e01 = *(const float2*)(er);
    float2 e23 = *(const float2*)(er + 2);
    float2 e45 = *(const float2*)(er + 4);
    aea.w[0] = f2bf_pk(e01.x, e01.y);
    aea.w[1] = f2bf_pk(e23.x, e23.y);
    aea.w[2] = f2bf_pk(e45.x, e45.y);
  }

  const short8* Bp = (const short8*)pk3;
  f32x16 acc = {0.f, 0.f, 0.f, 0.f, 0.f, 0.f, 0.f, 0.f,
                0.f, 0.f, 0.f, 0.f, 0.f, 0.f, 0.f, 0.f};
  #pragma unroll
  for (int t = 0; t < 4; t++)
    acc = __builtin_amdgcn_mfma_f32_32x32x16_bf16(hs[t], Bp[t * 64 + lane], acc, 0, 0, 0);
  #pragma unroll
  for (int t = 0; t < 4; t++)
    acc = __builtin_amdgcn_mfma_f32_32x32x16_bf16(hd[t], Bp[(4 + t) * 64 + lane], acc, 0, 0, 0);
  #pragma unroll
  for (int t = 0; t < 4; t++)
    acc = __builtin_amdgcn_mfma_f32_32x32x16_bf16(ad[t].s8, Bp[(8 + t) * 64 + lane], acc, 0, 0, 0);
  #pragma unroll
  for (int t = 0; t < 4; t++)
    acc = __builtin_amdgcn_mfma_f32_32x32x16_bf16(pd[t].s8, Bp[(12 + t) * 64 + lane], acc, 0, 0, 0);
  acc = __builtin_amdgcn_mfma_f32_32x32x16_bf16(aea.s8, Bp[16 * 64 + lane], acc, 0, 0, 0);

  float* Z = lds + wv * 1056;
  float b1v = B1[r];
  #pragma unroll
  for (int i = 0; i < 16; i++) {
    int row = (i & 3) + 8 * (i >> 2) + 4 * u;
    Z[r * 33 + row] = fmaxf(acc[i] + b1v, 0.f);
  }

  int m = lane & 15, g = lane >> 4;
  float bias2 = B2[m];
  float w3v = W3[m];
  #pragma unroll
  for (int q = 0; q < 2; q++) {
    u8 A2;
    #pragma unroll
    for (int j2 = 0; j2 < 4; j2++)
      A2.w[j2] = f2bf_pk(Z[(g * 8 + 2 * j2) * 33 + q * 16 + m],
                         Z[(g * 8 + 2 * j2 + 1) * 33 + q * 16 + m]);
    f32x4 acc2 = {0.f, 0.f, 0.f, 0.f};
    acc2 = __builtin_amdgcn_mfma_f32_16x16x32_bf16(A2.s8, ((const short8*)pk2)[lane], acc2, 0, 0, 0);

    float t0 = fmaxf(acc2[0] + bias2, 0.f) * w3v;
    float t1 = fmaxf(acc2[1] + bias2, 0.f) * w3v;
    float t2 = fmaxf(acc2[2] + bias2, 0.f) * w3v;
    float t3 = fmaxf(acc2[3] + bias2, 0.f) * w3v;
    #pragma unroll
    for (int off = 1; off < 16; off <<= 1) {
      t0 += __shfl_xor(t0, off, 64);
      t1 += __shfl_xor(t1, off, 64);
      t2 += __shfl_xor(t2, off, 64);
      t3 += __shfl_xor(t3, off, 64);
    }
    if (m < 4) {
      float val = (m == 0) ? t0 : (m == 1) ? t1 : (m == 2) ? t2 : t3;
      out[e0 + q * 16 + g * 4 + m] = val + B3[0];
    }
  }
}

extern "C" void kernel_launch(void* const* d_in, const int* in_sizes, int n_in,
                              void* d_out, int out_size, void* d_ws, size_t ws_size,
                              hipStream_t stream) {
  const float* x      = (const float*)d_in[0];
  const int*   ei     = (const int*)d_in[1];
  const float* ea     = (const float*)d_in[2];
  const float* w0     = (const float*)d_in[3];
  const float* root0  = (const float*)d_in[4];
  const float* b0     = (const float*)d_in[5];
  const float* w1     = (const float*)d_in[6];
  const float* root1  = (const float*)d_in[7];
  const float* b1     = (const float*)d_in[8];
  const float* w2     = (const float*)d_in[9];
  const float* root2  = (const float*)d_in[10];
  const float* b2     = (const float*)d_in[11];
  const float* ln_g0  = (const float*)d_in[12];
  const float* ln_b0  = (const float*)d_in[13];
  const float* ln_g1  = (const float*)d_in[14];
  const float* ln_b1  = (const float*)d_in[15];
  const float* ln_g2  = (const float*)d_in[16];
  const float* ln_b2  = (const float*)d_in[17];
  const float* res_w  = (const float*)d_in[18];
  const float* res_b  = (const float*)d_in[19];
  const float* dec_w1 = (const float*)d_in[20];
  const float* dec_b1 = (const float*)d_in[21];
  const float* dec_w2 = (const float*)d_in[22];
  const float* dec_b2 = (const float*)d_in[23];
  const float* dec_w3 = (const float*)d_in[24];
  const float* dec_b3 = (const float*)d_in[25];

  char* ws = (char*)d_ws;
  unsigned char* r8 = (unsigned char*)(ws + 0);        //    800,000 B
  int*   cntR    = (int*)(ws + 800000);                //    600,000 B (memset 0)
  float* agg0    = (float*)(ws + 1400000);             //  1,800,000 B
  int*   bsum    = (int*)(ws + 3200000);               //      1,024 B
  int*   off3    = (int*)(ws + 3201024);               //    600,000 B
  int*   cursor3 = (int*)(ws + 3801024);               //    600,000 B
  float* dinv    = (float*)(ws + 4401024);             //    600,000 B
  unsigned short* sorted = (unsigned short*)(ws + 5001024); // 1,600,000 B
  unsigned short* hcat = (unsigned short*)(ws + 6601024);   // 25,600,000 B
  unsigned short* pk3  = (unsigned short*)(ws + 32201024);  //     17,408 B
  unsigned short* pkw2 = (unsigned short*)(ws + 32218432);  //      1,024 B
  unsigned short* pkl1 = (unsigned short*)(ws + 32219456);  //     32,768 B
  unsigned short* pkl2 = (unsigned short*)(ws + 32252224);  //     32,768 B
  unsigned short* hb   = (unsigned short*)(ws + 32284992);  //  6,400,000 B (end 38,684,992)

  hipMemsetAsync(cntR, 0, 600000, stream);

  edge_prep<<<(NE + 255) / 256, 256, 0, stream>>>(ei, ea, cntR, r8);
  scanA<<<NB, 256, 0, stream>>>(cntR, bsum);
  scanB<<<1, 256, 0, stream>>>(bsum);
  scanC<<<NB, 256, 0, stream>>>(cntR, bsum, off3, cursor3, dinv);
  scatter_kernel<<<(NE + 255) / 256, 256, 0, stream>>>(ei, r8, cursor3, sorted);
  agg0_pack<<<3 + (NN + 63) / 64, 256, 0, stream>>>(x, off3, cntR, sorted, agg0,
                                                    dec_w1, dec_w2, root1, w1, root2, w2,
                                                    pk3, pkw2, pkl1, pkl2);

  const int node0_blocks = (NN / 8 + 3) / 4;          // 8 nodes/wave
  const int agg_blocks   = (NN / 4 + 3) / 4;          // 4 nodes/wave
  const int mfma_blocks  = (NN / 16 + 3) / 4;         // 16 nodes/wave

  node0_kernel<<<node0_blocks, 256, 0, stream>>>(x, agg0, dinv, w0, root0, b0,
                                                 res_w, res_b, ln_g0, ln_b0, hcat, hb);

  agg_csr<<<agg_blocks, 256, 0, stream>>>(hb, hcat, off3, cntR, sorted, dinv);
  node_mfma<<<mfma_blocks, 256, 0, stream>>>(hcat, pkl1, b1, ln_g1, ln_b1, hb, 1);

  agg_csr<<<agg_blocks, 256, 0, stream>>>(hb, hcat, off3, cntR, sorted, dinv);
  node_mfma<<<mfma_blocks, 256, 0, stream>>>(hcat, pkl2, b2, ln_g2, ln_b2, hb, 0);

  decoder_mfma<<<NE / 128, 256, 0, stream>>>(hb, ei, ea, pk3, pkw2, dec_b1,
                                             dec_b2, dec_w3, dec_b3, (float*)d_out);
}